// Round 1
// 336.236 us; speedup vs baseline: 1.0972x; 1.0972x over previous
//
#include <hip/hip_runtime.h>

#define B_ 4
#define T_ 2048
#define D_ 1024
#define H_ 16
#define DK_ 64
#define M_ (B_*T_)   // 8192 rows

typedef __bf16 bf16;
typedef __bf16 bf16x8 __attribute__((ext_vector_type(8)));
typedef __bf16 bf16x4 __attribute__((ext_vector_type(4)));
typedef short s16x4 __attribute__((ext_vector_type(4)));
typedef float f32x4 __attribute__((ext_vector_type(4)));

__device__ __forceinline__ f32x4 zero4() { f32x4 v = {0.f, 0.f, 0.f, 0.f}; return v; }

// bare-instruction exp2: exactly 1 VALU issue (s_nop covers the trans-op wait state on SALU)
__device__ __forceinline__ float fexp2(float x) {
  float r;
  asm("v_exp_f32 %0, %1\n\ts_nop 0" : "=v"(r) : "v"(x));
  return r;
}

// 3-input max, 1 VALU issue
__device__ __forceinline__ float max3f(float a, float b, float c) {
  float r;
  asm("v_max3_f32 %0, %1, %2, %3" : "=v"(r) : "v"(a), "v"(b), "v"(c));
  return r;
}

// async global->LDS, 16B per lane; LDS base wave-uniform, HW adds lane*16
__device__ __forceinline__ void g2l16(const void* g, void* l) {
  __builtin_amdgcn_global_load_lds(
      (const __attribute__((address_space(1))) void*)g,
      (__attribute__((address_space(3))) void*)l, 16, 0, 0);
}

// ---------------- x cast: fp32 -> bf16, 8 elems/thread ----------------
__global__ __launch_bounds__(256) void cast_bf16(const float* __restrict__ src,
                                                 bf16* __restrict__ dst) {
  const size_t i = ((size_t)blockIdx.x * 256 + threadIdx.x) * 8;
  float4 a = *(const float4*)(src + i);
  float4 b = *(const float4*)(src + i + 4);
  bf16x8 v;
  v[0] = (bf16)a.x; v[1] = (bf16)a.y; v[2] = (bf16)a.z; v[3] = (bf16)a.w;
  v[4] = (bf16)b.x; v[5] = (bf16)b.y; v[6] = (bf16)b.z; v[7] = (bf16)b.w;
  *(bf16x8*)(dst + i) = v;
}

// ---------------- weight transpose + cast: dst[C][R] = (bf16)src[R][C] ----------------
__global__ __launch_bounds__(256) void transpose_wf(const float* __restrict__ src,
                                                    bf16* __restrict__ dst, int R, int C) {
  __shared__ alignas(16) bf16 ts[64 * 65];
  const int tid = threadIdx.x;
  const int r0 = blockIdx.x * 64, c0 = blockIdx.y * 64;
  {
    int rr = tid >> 2, cc = (tid & 3) * 16;
    const float4* p4 = (const float4*)(src + (size_t)(r0 + rr) * C + c0 + cc);
    float fv[16];
#pragma unroll
    for (int q = 0; q < 4; ++q) *(float4*)&fv[q * 4] = p4[q];
#pragma unroll
    for (int i = 0; i < 16; ++i) ts[(cc + i) * 65 + rr] = (bf16)fv[i];
  }
  __syncthreads();
  {
    int rr = tid >> 2, cc = (tid & 3) * 16;
    bf16x8 a, b;
#pragma unroll
    for (int i = 0; i < 8; ++i) a[i] = ts[rr * 65 + cc + i];
#pragma unroll
    for (int i = 0; i < 8; ++i) b[i] = ts[rr * 65 + cc + 8 + i];
    bf16* q = dst + (size_t)(c0 + rr) * R + r0 + cc;
    *(bf16x8*)q = a;
    *(bf16x8*)(q + 8) = b;
  }
}

// ---------------- V transpose: Vt[b][h][f][t] = qkv[b*T+t][2D + h*64 + f] ----------------
__global__ __launch_bounds__(256) void transpose_v(const bf16* __restrict__ qkv,
                                                   bf16* __restrict__ Vt) {
  __shared__ alignas(16) bf16 ts[64 * 65];
  int bid = blockIdx.x;
  const int tt = bid & 31; bid >>= 5;
  const int h = bid & 15;  const int b = bid >> 4;
  const int t0 = tt * 64;
  const int tid = threadIdx.x;
  {
    int tok = tid >> 2, fc = (tid & 3) * 16;
    const bf16* p = qkv + (size_t)(b * T_ + t0 + tok) * (3 * D_) + 2 * D_ + h * DK_ + fc;
    bf16x8 a = *(const bf16x8*)p;
    bf16x8 c = *(const bf16x8*)(p + 8);
#pragma unroll
    for (int i = 0; i < 8; ++i) ts[(fc + i) * 65 + tok] = a[i];
#pragma unroll
    for (int i = 0; i < 8; ++i) ts[(fc + 8 + i) * 65 + tok] = c[i];
  }
  __syncthreads();
  {
    int f = tid >> 2, tc = (tid & 3) * 16;
    bf16x8 a, c;
#pragma unroll
    for (int i = 0; i < 8; ++i) a[i] = ts[f * 65 + tc + i];
#pragma unroll
    for (int i = 0; i < 8; ++i) c[i] = ts[f * 65 + tc + 8 + i];
    bf16* q = Vt + ((size_t)(b * H_ + h) * DK_ + f) * T_ + t0 + tc;
    *(bf16x8*)q = a;
    *(bf16x8*)(q + 8) = c;
  }
}

// ---------------- GEMM: C[M][N] = A[M][K] @ Bt[N][K]^T + bias ----------------
// ASRC=0: A fp32, cast during register staging. ASRC=1: A bf16, DMA-staged.
// B always DMA-staged (m97 pattern). FUSE: Cf32 = C + resid(fp32), stride N.
template <int ASRC, bool FUSE>
__global__ __launch_bounds__(256) void gemm128(const void* __restrict__ Av,
                                               const bf16* __restrict__ Bt,
                                               const float* __restrict__ bias,
                                               bf16* __restrict__ Cbf,
                                               float* __restrict__ Cf,
                                               const float* __restrict__ resid,
                                               int N, int K, int lda, int ldc) {
  __shared__ alignas(16) bf16 As[128 * 32];
  __shared__ alignas(16) bf16 Bs[128 * 32];
  const int tid = threadIdx.x;
  const int wid = tid >> 6, lane = tid & 63, quad = lane >> 4, l16 = lane & 15;
  const int m0 = blockIdx.x * 128, n0 = blockIdx.y * 128;
  const int wr = (wid >> 1) * 64, wc = (wid & 1) * 64;

  f32x4 acc[4][4];
#pragma unroll
  for (int i = 0; i < 4; ++i)
#pragma unroll
    for (int j = 0; j < 4; ++j) acc[i][j] = zero4();

  for (int k0 = 0; k0 < K; k0 += 32) {
    bf16x8 ar[2];
    if (ASRC == 0) {
#pragma unroll
      for (int p = 0; p < 2; ++p) {
        int t = p * 256 + tid;
        int row = t >> 2, kc = (t & 3) * 8;
        const float* ap = (const float*)Av + (size_t)(m0 + row) * lda + k0 + kc;
        float4 a0 = *(const float4*)ap, a1 = *(const float4*)(ap + 4);
        bf16x8 v;
        v[0] = (bf16)a0.x; v[1] = (bf16)a0.y; v[2] = (bf16)a0.z; v[3] = (bf16)a0.w;
        v[4] = (bf16)a1.x; v[5] = (bf16)a1.y; v[6] = (bf16)a1.z; v[7] = (bf16)a1.w;
        ar[p] = v;
      }
    }
    __syncthreads();  // previous iteration's LDS reads complete
#pragma unroll
    for (int p = 0; p < 2; ++p) {
      int t = p * 256 + tid;
      int row = t >> 2, kc = (t & 3) * 8;
      g2l16(Bt + (size_t)(n0 + row) * K + k0 + kc, (char*)Bs + p * 4096 + wid * 1024);
      if (ASRC == 1)
        g2l16((const bf16*)Av + (size_t)(m0 + row) * lda + k0 + kc,
              (char*)As + p * 4096 + wid * 1024);
      else
        *(bf16x8*)&As[row * 32 + kc] = ar[p];
    }
    __syncthreads();
    bf16x8 af[4], bfr[4];
#pragma unroll
    for (int i = 0; i < 4; ++i)
      af[i] = *(const bf16x8*)&As[(wr + i * 16 + l16) * 32 + quad * 8];
#pragma unroll
    for (int j = 0; j < 4; ++j)
      bfr[j] = *(const bf16x8*)&Bs[(wc + j * 16 + l16) * 32 + quad * 8];
#pragma unroll
    for (int i = 0; i < 4; ++i)
#pragma unroll
      for (int j = 0; j < 4; ++j)
        acc[i][j] = __builtin_amdgcn_mfma_f32_16x16x32_bf16(af[i], bfr[j], acc[i][j], 0, 0, 0);
  }

#pragma unroll
  for (int i = 0; i < 4; ++i) {
#pragma unroll
    for (int j = 0; j < 4; ++j) {
      const int col = n0 + wc + j * 16 + l16;
      const float bv = bias[col];
#pragma unroll
      for (int r = 0; r < 4; ++r) {
        const int row = m0 + wr + i * 16 + quad * 4 + r;
        const float v = acc[i][j][r] + bv;
        if (FUSE) {
          const size_t off = (size_t)row * N + col;
          Cf[off] = v + resid[off];
        } else {
          Cbf[(size_t)row * ldc + col] = (bf16)v;
        }
      }
    }
  }
}

// ---------------- flash attention: block = (b, h, 128 q-rows), 8 waves x 16 rows ----------------
// S^T = K Q^T (C-layout row=key, col=qrow); P stays in registers feeding 16x16x16 PV.
// Softmax in log2 domain. Register-prefetch software pipeline + defer-max (T13) +
// max3 tree reduce (T17) + bare v_exp_f32 + setprio around MFMA clusters (T5).
__global__ __launch_bounds__(512) void attn128(const bf16* __restrict__ qkv,
                                               const bf16* __restrict__ Vt,
                                               bf16* __restrict__ out) {
  __shared__ alignas(16) bf16 Ks[128 * 72];      // [key][f], stride 72
  __shared__ alignas(16) bf16 Vs[64 * 136];      // [f][key], stride 136
  const int tid = threadIdx.x;
  const int wid = tid >> 6, lane = tid & 63, quad = lane >> 4, l16 = lane & 15;
  const int bid = blockIdx.x;
  const int qb = bid & 15, h = (bid >> 4) & 15, b = bid >> 8;
  const int q0 = qb * 128;

  // staging addresses (thread-invariant across tiles except kt*128)
  const int skey = tid >> 3, sf = (tid & 7) * 8;          // K: tid covers 64 keys x 8 f-chunks
  const int svf = tid >> 4, skc = (tid & 15) * 8;         // V: 32 f-rows x 16 key-chunks
  const bf16* kbase = qkv + (size_t)(b * T_ + skey) * (3 * D_) + D_ + h * DK_ + sf;
  const bf16* vbase = Vt + ((size_t)(b * H_ + h) * DK_ + svf) * T_ + skc;

  // Q as MFMA B-operand (k=quad*8+j, n=qrow=l16), pre-scaled by log2e/8
  const float SC = 0.125f * 1.44269504f;
  bf16x8 qf[2];
  {
    const bf16* qp = qkv + (size_t)(b * T_ + q0 + wid * 16 + l16) * (3 * D_) + h * DK_ + quad * 8;
    qf[0] = *(const bf16x8*)qp;
    qf[1] = *(const bf16x8*)(qp + 32);
#pragma unroll
    for (int i = 0; i < 8; ++i) { qf[0][i] = (bf16)((float)qf[0][i] * SC);
                                  qf[1][i] = (bf16)((float)qf[1][i] * SC); }
  }

  float mi = -1e30f, li = 0.f;   // per-lane: qrow = l16 (replicated across quads)
  f32x4 o[4];                    // o[ft][r] = O[qrow=quad*4+r][f=ft*16+l16]
#pragma unroll
  for (int ft = 0; ft < 4; ++ft) o[ft] = zero4();

  // prefetch tile 0 into registers
  bf16x8 kr[2], vr[2];
#pragma unroll
  for (int p = 0; p < 2; ++p) {
    kr[p] = *(const bf16x8*)(kbase + (size_t)(p * 64) * (3 * D_));
    vr[p] = *(const bf16x8*)(vbase + (size_t)(p * 32) * T_);
  }

  for (int kt = 0; kt < T_ / 128; ++kt) {
    __syncthreads();               // prior tile's LDS reads complete
#pragma unroll
    for (int p = 0; p < 2; ++p) {
      *(bf16x8*)&Ks[(skey + p * 64) * 72 + sf] = kr[p];
      *(bf16x8*)&Vs[(svf + p * 32) * 136 + skc] = vr[p];
    }
    __syncthreads();
    if (kt + 1 < T_ / 128) {       // issue next tile's loads; consumed next iteration
      const size_t koff = (size_t)(kt + 1) * 128;
#pragma unroll
      for (int p = 0; p < 2; ++p) {
        kr[p] = *(const bf16x8*)(kbase + (koff + p * 64) * (3 * D_));
        vr[p] = *(const bf16x8*)(vbase + (size_t)(p * 32) * T_ + koff);
      }
    }

    // S^T tile (log2 domain): sv[nt] reg r = S2[key = nt*16+quad*4+r][qrow = l16]
    f32x4 sv[8];
#pragma unroll
    for (int nt = 0; nt < 8; ++nt) sv[nt] = zero4();
    __builtin_amdgcn_s_setprio(1);
#pragma unroll
    for (int nt = 0; nt < 8; ++nt)
#pragma unroll
      for (int ks = 0; ks < 2; ++ks) {
        bf16x8 kf = *(const bf16x8*)&Ks[(nt * 16 + l16) * 72 + ks * 32 + quad * 8];
        sv[nt] = __builtin_amdgcn_mfma_f32_16x16x32_bf16(kf, qf[ks], sv[nt], 0, 0, 0);
      }
    __builtin_amdgcn_s_setprio(0);

    // tile max via two parallel v_max3 chains (16 issues for 32 values)
    float t0 = max3f(sv[0][0], sv[0][1], sv[0][2]);
    float t1 = max3f(sv[0][3], sv[1][0], sv[1][1]);
    t0 = max3f(t0, sv[1][2], sv[1][3]);
#pragma unroll
    for (int nt = 2; nt < 8; nt += 2) {
      t0 = max3f(t0, sv[nt][0], sv[nt][1]);
      t1 = max3f(t1, sv[nt][2], sv[nt][3]);
      t0 = max3f(t0, sv[nt + 1][0], sv[nt + 1][1]);
      t1 = max3f(t1, sv[nt + 1][2], sv[nt + 1][3]);
    }
    float tmax = fmaxf(t0, t1);
    tmax = fmaxf(tmax, __shfl_xor(tmax, 16, 64));
    tmax = fmaxf(tmax, __shfl_xor(tmax, 32, 64));

    // defer-max (T13): only rescale when the running max grew by more than 8 (log2)
    if (!__all(tmax <= mi + 8.f)) {
      const float nm = fmaxf(mi, tmax);
      const float alpha = fexp2(mi - nm);
      mi = nm;
      li *= alpha;
      // rescale O: row quad*4+r's alpha lives at lane quad*4+r
#pragma unroll
      for (int r = 0; r < 4; ++r) {
        const float ar = __shfl(alpha, quad * 4 + r, 64);
#pragma unroll
        for (int ft = 0; ft < 4; ++ft) o[ft][r] *= ar;
      }
    }

    // P = exp2(S - mi), bounded by 2^8; vector sum with 4-way ILP
    f32x4 s4 = zero4();
#pragma unroll
    for (int nt = 0; nt < 8; ++nt) {
      f32x4 d = sv[nt] - mi;
      d[0] = fexp2(d[0]); d[1] = fexp2(d[1]); d[2] = fexp2(d[2]); d[3] = fexp2(d[3]);
      sv[nt] = d;
      s4 += d;
    }
    float s = (s4[0] + s4[1]) + (s4[2] + s4[3]);
    s += __shfl_xor(s, 16, 64);
    s += __shfl_xor(s, 32, 64);
    li += s;

    // O += P V via 16x16x16 (A=P in registers: k=key=ks*16+quad*4+j)
    __builtin_amdgcn_s_setprio(1);
#pragma unroll
    for (int ks = 0; ks < 8; ++ks) {
      union { bf16x4 b; s16x4 s; } pf;
#pragma unroll
      for (int j = 0; j < 4; ++j) pf.b[j] = (bf16)sv[ks][j];
#pragma unroll
      for (int ft = 0; ft < 4; ++ft) {
        const s16x4 vf = *(const s16x4*)&Vs[(ft * 16 + l16) * 136 + ks * 16 + quad * 4];
        o[ft] = __builtin_amdgcn_mfma_f32_16x16x16bf16_1k(pf.s, vf, o[ft], 0, 0, 0);
      }
    }
    __builtin_amdgcn_s_setprio(0);
  }

  // epilogue: normalize rows (li for qrow=quad*4+r lives at lane quad*4+r)
#pragma unroll
  for (int r = 0; r < 4; ++r) {
    const float inv = 1.0f / __shfl(li, quad * 4 + r, 64);
    const int row = b * T_ + q0 + wid * 16 + quad * 4 + r;
#pragma unroll
    for (int ft = 0; ft < 4; ++ft)
      out[(size_t)row * (3 * D_) + h * DK_ + ft * 16 + l16] = (bf16)(o[ft][r] * inv);
  }
}

// ---------------- layernorm: one wave per row, in-place, no LDS/barrier ----------------
__global__ __launch_bounds__(256) void ln_out(float* __restrict__ res,
                                              const float* __restrict__ gamma,
                                              const float* __restrict__ beta) {
  const int row = blockIdx.x * 4 + (threadIdx.x >> 6);
  const int lane = threadIdx.x & 63;
  float4 v[4];
  float s = 0.f, q = 0.f;
#pragma unroll
  for (int p = 0; p < 4; ++p) {
    v[p] = *(const float4*)(res + (size_t)row * D_ + p * 256 + lane * 4);
    s += v[p].x + v[p].y + v[p].z + v[p].w;
    q += v[p].x * v[p].x + v[p].y * v[p].y + v[p].z * v[p].z + v[p].w * v[p].w;
  }
#pragma unroll
  for (int m = 1; m < 64; m <<= 1) { s += __shfl_xor(s, m, 64); q += __shfl_xor(q, m, 64); }
  const float mu = s * (1.0f / D_);
  const float var = q * (1.0f / D_) - mu * mu;
  const float rstd = rsqrtf(var + 1e-5f);
#pragma unroll
  for (int p = 0; p < 4; ++p) {
    const int c = p * 256 + lane * 4;
    const float4 g = *(const float4*)(gamma + c);
    const float4 be = *(const float4*)(beta + c);
    float4 ov;
    ov.x = (v[p].x - mu) * rstd * g.x + be.x;
    ov.y = (v[p].y - mu) * rstd * g.y + be.y;
    ov.z = (v[p].z - mu) * rstd * g.z + be.z;
    ov.w = (v[p].w - mu) * rstd * g.w + be.w;
    *(float4*)(res + (size_t)row * D_ + c) = ov;
  }
}

extern "C" void kernel_launch(void* const* d_in, const int* in_sizes, int n_in,
                              void* d_out, int out_size, void* d_ws, size_t ws_size,
                              hipStream_t stream) {
  const float* x     = (const float*)d_in[0];
  const float* Wqkv  = (const float*)d_in[1];
  const float* bqkv  = (const float*)d_in[2];
  const float* Wout  = (const float*)d_in[3];
  const float* bout  = (const float*)d_in[4];
  const float* gamma = (const float*)d_in[5];
  const float* beta  = (const float*)d_in[6];
  float* out = (float*)d_out;  // fp32 residual buffer too (LN in-place)

  // workspace layout (75.5 MB, proven footprint):
  char* ws = (char*)d_ws;
  bf16* WqkvT = (bf16*)ws; ws += (size_t)3 * D_ * D_ * 2;        // [3072][1024]
  bf16* WoutT = (bf16*)ws; ws += (size_t)D_ * D_ * 2;            // [1024][1024]
  bf16* qkv   = (bf16*)ws; ws += (size_t)M_ * 3 * D_ * 2;        // [8192][3072]
  bf16* Vt    = (bf16*)ws;                                       // [4][16][64][2048]
  bf16* attn  = qkv + 2 * D_;  // attn output overwrites qkv's V columns (dead after transpose_v)
  bf16* xb    = Vt;            // x in bf16 aliases Vt (dead before transpose_v runs)

  transpose_wf<<<dim3(D_ / 64, 3 * D_ / 64), 256, 0, stream>>>(Wqkv, WqkvT, D_, 3 * D_);
  transpose_wf<<<dim3(D_ / 64, D_ / 64), 256, 0, stream>>>(Wout, WoutT, D_, D_);
  cast_bf16<<<M_ * D_ / (256 * 8), 256, 0, stream>>>(x, xb);
  gemm128<1, false><<<dim3(M_ / 128, 3 * D_ / 128), 256, 0, stream>>>(
      xb, WqkvT, bqkv, qkv, nullptr, nullptr, 3 * D_, D_, D_, 3 * D_);
  transpose_v<<<B_ * H_ * (T_ / 64), 256, 0, stream>>>(qkv, Vt);
  attn128<<<B_ * H_ * (T_ / 128), 512, 0, stream>>>(qkv, Vt, attn);
  gemm128<1, true><<<dim3(M_ / 128, D_ / 128), 256, 0, stream>>>(
      attn, WoutT, bout, nullptr, out, x, D_, D_, 3 * D_, D_);
  ln_out<<<M_ / 4, 256, 0, stream>>>(out, gamma, beta);
}

// Round 3
// 333.158 us; speedup vs baseline: 1.1074x; 1.0092x over previous
//
#include <hip/hip_runtime.h>

#define B_ 4
#define T_ 2048
#define D_ 1024
#define H_ 16
#define DK_ 64
#define M_ (B_*T_)   // 8192 rows

typedef __bf16 bf16;
typedef __bf16 bf16x8 __attribute__((ext_vector_type(8)));
typedef __bf16 bf16x4 __attribute__((ext_vector_type(4)));
typedef short s16x4 __attribute__((ext_vector_type(4)));
typedef float f32x4 __attribute__((ext_vector_type(4)));

__device__ __forceinline__ f32x4 zero4() { f32x4 v = {0.f, 0.f, 0.f, 0.f}; return v; }

// bare-instruction exp2: exactly 1 VALU issue (s_nop covers the trans-op wait state on SALU)
__device__ __forceinline__ float fexp2(float x) {
  float r;
  asm("v_exp_f32 %0, %1\n\ts_nop 0" : "=v"(r) : "v"(x));
  return r;
}

// 3-input max, 1 VALU issue
__device__ __forceinline__ float max3f(float a, float b, float c) {
  float r;
  asm("v_max3_f32 %0, %1, %2, %3" : "=v"(r) : "v"(a), "v"(b), "v"(c));
  return r;
}

// async global->LDS, 16B per lane; LDS base wave-uniform, HW adds lane*16
__device__ __forceinline__ void g2l16(const void* g, void* l) {
  __builtin_amdgcn_global_load_lds(
      (const __attribute__((address_space(1))) void*)g,
      (__attribute__((address_space(3))) void*)l, 16, 0, 0);
}

// ---------------- x cast: fp32 -> bf16, 8 elems/thread ----------------
__global__ __launch_bounds__(256) void cast_bf16(const float* __restrict__ src,
                                                 bf16* __restrict__ dst) {
  const size_t i = ((size_t)blockIdx.x * 256 + threadIdx.x) * 8;
  float4 a = *(const float4*)(src + i);
  float4 b = *(const float4*)(src + i + 4);
  bf16x8 v;
  v[0] = (bf16)a.x; v[1] = (bf16)a.y; v[2] = (bf16)a.z; v[3] = (bf16)a.w;
  v[4] = (bf16)b.x; v[5] = (bf16)b.y; v[6] = (bf16)b.z; v[7] = (bf16)b.w;
  *(bf16x8*)(dst + i) = v;
}

// ---------------- weight transpose + cast: dst[C][R] = (bf16)src[R][C] ----------------
__global__ __launch_bounds__(256) void transpose_wf(const float* __restrict__ src,
                                                    bf16* __restrict__ dst, int R, int C) {
  __shared__ alignas(16) bf16 ts[64 * 65];
  const int tid = threadIdx.x;
  const int r0 = blockIdx.x * 64, c0 = blockIdx.y * 64;
  {
    int rr = tid >> 2, cc = (tid & 3) * 16;
    const float4* p4 = (const float4*)(src + (size_t)(r0 + rr) * C + c0 + cc);
    float fv[16];
#pragma unroll
    for (int q = 0; q < 4; ++q) *(float4*)&fv[q * 4] = p4[q];
#pragma unroll
    for (int i = 0; i < 16; ++i) ts[(cc + i) * 65 + rr] = (bf16)fv[i];
  }
  __syncthreads();
  {
    int rr = tid >> 2, cc = (tid & 3) * 16;
    bf16x8 a, b;
#pragma unroll
    for (int i = 0; i < 8; ++i) a[i] = ts[rr * 65 + cc + i];
#pragma unroll
    for (int i = 0; i < 8; ++i) b[i] = ts[rr * 65 + cc + 8 + i];
    bf16* q = dst + (size_t)(c0 + rr) * R + r0 + cc;
    *(bf16x8*)q = a;
    *(bf16x8*)(q + 8) = b;
  }
}

// ---------------- V transpose: Vt[b][h][f][t] = qkv[b*T+t][2D + h*64 + f] ----------------
__global__ __launch_bounds__(256) void transpose_v(const bf16* __restrict__ qkv,
                                                   bf16* __restrict__ Vt) {
  __shared__ alignas(16) bf16 ts[64 * 65];
  int bid = blockIdx.x;
  const int tt = bid & 31; bid >>= 5;
  const int h = bid & 15;  const int b = bid >> 4;
  const int t0 = tt * 64;
  const int tid = threadIdx.x;
  {
    int tok = tid >> 2, fc = (tid & 3) * 16;
    const bf16* p = qkv + (size_t)(b * T_ + t0 + tok) * (3 * D_) + 2 * D_ + h * DK_ + fc;
    bf16x8 a = *(const bf16x8*)p;
    bf16x8 c = *(const bf16x8*)(p + 8);
#pragma unroll
    for (int i = 0; i < 8; ++i) ts[(fc + i) * 65 + tok] = a[i];
#pragma unroll
    for (int i = 0; i < 8; ++i) ts[(fc + 8 + i) * 65 + tok] = c[i];
  }
  __syncthreads();
  {
    int f = tid >> 2, tc = (tid & 3) * 16;
    bf16x8 a, c;
#pragma unroll
    for (int i = 0; i < 8; ++i) a[i] = ts[f * 65 + tc + i];
#pragma unroll
    for (int i = 0; i < 8; ++i) c[i] = ts[f * 65 + tc + 8 + i];
    bf16* q = Vt + ((size_t)(b * H_ + h) * DK_ + f) * T_ + t0 + tc;
    *(bf16x8*)q = a;
    *(bf16x8*)(q + 8) = c;
  }
}

// ---------------- GEMM: C[M][N] = A[M][K] @ Bt[N][K]^T + bias ----------------
template <int ASRC, bool FUSE>
__global__ __launch_bounds__(256) void gemm128(const void* __restrict__ Av,
                                               const bf16* __restrict__ Bt,
                                               const float* __restrict__ bias,
                                               bf16* __restrict__ Cbf,
                                               float* __restrict__ Cf,
                                               const float* __restrict__ resid,
                                               int N, int K, int lda, int ldc) {
  __shared__ alignas(16) bf16 As[128 * 32];
  __shared__ alignas(16) bf16 Bs[128 * 32];
  const int tid = threadIdx.x;
  const int wid = tid >> 6, lane = tid & 63, quad = lane >> 4, l16 = lane & 15;
  const int m0 = blockIdx.x * 128, n0 = blockIdx.y * 128;
  const int wr = (wid >> 1) * 64, wc = (wid & 1) * 64;

  f32x4 acc[4][4];
#pragma unroll
  for (int i = 0; i < 4; ++i)
#pragma unroll
    for (int j = 0; j < 4; ++j) acc[i][j] = zero4();

  for (int k0 = 0; k0 < K; k0 += 32) {
    bf16x8 ar[2];
    if (ASRC == 0) {
#pragma unroll
      for (int p = 0; p < 2; ++p) {
        int t = p * 256 + tid;
        int row = t >> 2, kc = (t & 3) * 8;
        const float* ap = (const float*)Av + (size_t)(m0 + row) * lda + k0 + kc;
        float4 a0 = *(const float4*)ap, a1 = *(const float4*)(ap + 4);
        bf16x8 v;
        v[0] = (bf16)a0.x; v[1] = (bf16)a0.y; v[2] = (bf16)a0.z; v[3] = (bf16)a0.w;
        v[4] = (bf16)a1.x; v[5] = (bf16)a1.y; v[6] = (bf16)a1.z; v[7] = (bf16)a1.w;
        ar[p] = v;
      }
    }
    __syncthreads();  // previous iteration's LDS reads complete
#pragma unroll
    for (int p = 0; p < 2; ++p) {
      int t = p * 256 + tid;
      int row = t >> 2, kc = (t & 3) * 8;
      g2l16(Bt + (size_t)(n0 + row) * K + k0 + kc, (char*)Bs + p * 4096 + wid * 1024);
      if (ASRC == 1)
        g2l16((const bf16*)Av + (size_t)(m0 + row) * lda + k0 + kc,
              (char*)As + p * 4096 + wid * 1024);
      else
        *(bf16x8*)&As[row * 32 + kc] = ar[p];
    }
    __syncthreads();
    bf16x8 af[4], bfr[4];
#pragma unroll
    for (int i = 0; i < 4; ++i)
      af[i] = *(const bf16x8*)&As[(wr + i * 16 + l16) * 32 + quad * 8];
#pragma unroll
    for (int j = 0; j < 4; ++j)
      bfr[j] = *(const bf16x8*)&Bs[(wc + j * 16 + l16) * 32 + quad * 8];
#pragma unroll
    for (int i = 0; i < 4; ++i)
#pragma unroll
      for (int j = 0; j < 4; ++j)
        acc[i][j] = __builtin_amdgcn_mfma_f32_16x16x32_bf16(af[i], bfr[j], acc[i][j], 0, 0, 0);
  }

#pragma unroll
  for (int i = 0; i < 4; ++i) {
#pragma unroll
    for (int j = 0; j < 4; ++j) {
      const int col = n0 + wc + j * 16 + l16;
      const float bv = bias[col];
#pragma unroll
      for (int r = 0; r < 4; ++r) {
        const int row = m0 + wr + i * 16 + quad * 4 + r;
        const float v = acc[i][j][r] + bv;
        if (FUSE) {
          const size_t off = (size_t)row * N + col;
          Cf[off] = v + resid[off];
        } else {
          Cbf[(size_t)row * ldc + col] = (bf16)v;
        }
      }
    }
  }
}

// ---------------- flash attention: block = (b, h, 256 q-rows), 8 waves x 32 rows ----------------
// Each wave owns TWO 16-row q-halves (A: l16, B: l16+16). Every Ks/Vs LDS fragment
// read feeds two MFMAs -> LDS bytes per FLOP halved (LDS pipe was ~80% busy and the
// bottleneck). Scores packed to bf16 immediately after exp.
__global__ __launch_bounds__(512, 2) void attn256(const bf16* __restrict__ qkv,
                                                  const bf16* __restrict__ Vt,
                                                  bf16* __restrict__ out) {
  __shared__ alignas(16) bf16 Ks[128 * 72];      // [key][f], stride 72
  __shared__ alignas(16) bf16 Vs[64 * 136];      // [f][key], stride 136
  const int tid = threadIdx.x;
  const int wid = tid >> 6, lane = tid & 63, quad = lane >> 4, l16 = lane & 15;
  const int bid = blockIdx.x;
  const int qb = bid & 7, h = (bid >> 3) & 15, b = bid >> 7;
  const int q0 = qb * 256;

  // staging addresses (thread-invariant across tiles except kt*128)
  const int skey = tid >> 3, sf = (tid & 7) * 8;          // K: tid covers 64 keys x 8 f-chunks
  const int svf = tid >> 4, skc = (tid & 15) * 8;         // V: 32 f-rows x 16 key-chunks
  const bf16* kbase = qkv + (size_t)(b * T_ + skey) * (3 * D_) + D_ + h * DK_ + sf;
  const bf16* vbase = Vt + ((size_t)(b * H_ + h) * DK_ + svf) * T_ + skc;

  // Q as MFMA B-operand (k=quad*8+j, n=qrow=l16), pre-scaled by log2e/8
  const float SC = 0.125f * 1.44269504f;
  bf16x8 qA[2], qB[2];
  {
    const bf16* qpA = qkv + (size_t)(b * T_ + q0 + wid * 32 + l16) * (3 * D_) + h * DK_ + quad * 8;
    const bf16* qpB = qpA + (size_t)16 * (3 * D_);
    qA[0] = *(const bf16x8*)qpA;       qA[1] = *(const bf16x8*)(qpA + 32);
    qB[0] = *(const bf16x8*)qpB;       qB[1] = *(const bf16x8*)(qpB + 32);
#pragma unroll
    for (int i = 0; i < 8; ++i) {
      qA[0][i] = (bf16)((float)qA[0][i] * SC); qA[1][i] = (bf16)((float)qA[1][i] * SC);
      qB[0][i] = (bf16)((float)qB[0][i] * SC); qB[1][i] = (bf16)((float)qB[1][i] * SC);
    }
  }

  float miA = -1e30f, liA = 0.f, miB = -1e30f, liB = 0.f;
  f32x4 oA[4], oB[4];
#pragma unroll
  for (int ft = 0; ft < 4; ++ft) { oA[ft] = zero4(); oB[ft] = zero4(); }

  // prefetch tile 0 into registers
  bf16x8 kr[2], vr[2];
#pragma unroll
  for (int p = 0; p < 2; ++p) {
    kr[p] = *(const bf16x8*)(kbase + (size_t)(p * 64) * (3 * D_));
    vr[p] = *(const bf16x8*)(vbase + (size_t)(p * 32) * T_);
  }

  for (int kt = 0; kt < T_ / 128; ++kt) {
    __syncthreads();               // prior tile's LDS reads complete
#pragma unroll
    for (int p = 0; p < 2; ++p) {
      *(bf16x8*)&Ks[(skey + p * 64) * 72 + sf] = kr[p];
      *(bf16x8*)&Vs[(svf + p * 32) * 136 + skc] = vr[p];
    }
    __syncthreads();
    if (kt + 1 < T_ / 128) {       // issue next tile's loads; consumed next iteration
      const size_t koff = (size_t)(kt + 1) * 128;
#pragma unroll
      for (int p = 0; p < 2; ++p) {
        kr[p] = *(const bf16x8*)(kbase + (koff + p * 64) * (3 * D_));
        vr[p] = *(const bf16x8*)(vbase + (size_t)(p * 32) * T_ + koff);
      }
    }

    // S^T tiles for both q-halves: each kf read feeds 2 MFMAs
    f32x4 svA[8], svB[8];
#pragma unroll
    for (int nt = 0; nt < 8; ++nt) { svA[nt] = zero4(); svB[nt] = zero4(); }
    __builtin_amdgcn_s_setprio(1);
#pragma unroll
    for (int nt = 0; nt < 8; ++nt)
#pragma unroll
      for (int ks = 0; ks < 2; ++ks) {
        bf16x8 kf = *(const bf16x8*)&Ks[(nt * 16 + l16) * 72 + ks * 32 + quad * 8];
        svA[nt] = __builtin_amdgcn_mfma_f32_16x16x32_bf16(kf, qA[ks], svA[nt], 0, 0, 0);
        svB[nt] = __builtin_amdgcn_mfma_f32_16x16x32_bf16(kf, qB[ks], svB[nt], 0, 0, 0);
      }
    __builtin_amdgcn_s_setprio(0);

    // tile max via parallel v_max3 chains (per half)
    float a0 = max3f(svA[0][0], svA[0][1], svA[0][2]);
    float a1 = max3f(svA[0][3], svA[1][0], svA[1][1]);
    a0 = max3f(a0, svA[1][2], svA[1][3]);
    float b0 = max3f(svB[0][0], svB[0][1], svB[0][2]);
    float b1 = max3f(svB[0][3], svB[1][0], svB[1][1]);
    b0 = max3f(b0, svB[1][2], svB[1][3]);
#pragma unroll
    for (int nt = 2; nt < 8; nt += 2) {
      a0 = max3f(a0, svA[nt][0], svA[nt][1]);
      a1 = max3f(a1, svA[nt][2], svA[nt][3]);
      a0 = max3f(a0, svA[nt + 1][0], svA[nt + 1][1]);
      a1 = max3f(a1, svA[nt + 1][2], svA[nt + 1][3]);
      b0 = max3f(b0, svB[nt][0], svB[nt][1]);
      b1 = max3f(b1, svB[nt][2], svB[nt][3]);
      b0 = max3f(b0, svB[nt + 1][0], svB[nt + 1][1]);
      b1 = max3f(b1, svB[nt + 1][2], svB[nt + 1][3]);
    }
    float tA = fmaxf(a0, a1), tB = fmaxf(b0, b1);
    tA = fmaxf(tA, __shfl_xor(tA, 16, 64));
    tA = fmaxf(tA, __shfl_xor(tA, 32, 64));
    tB = fmaxf(tB, __shfl_xor(tB, 16, 64));
    tB = fmaxf(tB, __shfl_xor(tB, 32, 64));

    // defer-max (T13), per half
    if (!__all(tA <= miA + 8.f)) {
      const float nm = fmaxf(miA, tA);
      const float al = fexp2(miA - nm);
      miA = nm; liA *= al;
#pragma unroll
      for (int r = 0; r < 4; ++r) {
        const float ar = __shfl(al, quad * 4 + r, 64);
#pragma unroll
        for (int ft = 0; ft < 4; ++ft) oA[ft][r] *= ar;
      }
    }
    if (!__all(tB <= miB + 8.f)) {
      const float nm = fmaxf(miB, tB);
      const float al = fexp2(miB - nm);
      miB = nm; liB *= al;
#pragma unroll
      for (int r = 0; r < 4; ++r) {
        const float ar = __shfl(al, quad * 4 + r, 64);
#pragma unroll
        for (int ft = 0; ft < 4; ++ft) oB[ft][r] *= ar;
      }
    }

    // P = exp2(S - mi); pack to bf16 immediately (frees the fp32 score block)
    s16x4 pA[8], pB[8];
    f32x4 s4A = zero4(), s4B = zero4();
#pragma unroll
    for (int nt = 0; nt < 8; ++nt) {
      f32x4 dA = svA[nt] - miA;
      dA[0] = fexp2(dA[0]); dA[1] = fexp2(dA[1]); dA[2] = fexp2(dA[2]); dA[3] = fexp2(dA[3]);
      s4A += dA;
      union { bf16x4 b; s16x4 s; } ua;
#pragma unroll
      for (int j = 0; j < 4; ++j) ua.b[j] = (bf16)dA[j];
      pA[nt] = ua.s;
      f32x4 dB = svB[nt] - miB;
      dB[0] = fexp2(dB[0]); dB[1] = fexp2(dB[1]); dB[2] = fexp2(dB[2]); dB[3] = fexp2(dB[3]);
      s4B += dB;
      union { bf16x4 b; s16x4 s; } ub;
#pragma unroll
      for (int j = 0; j < 4; ++j) ub.b[j] = (bf16)dB[j];
      pB[nt] = ub.s;
    }
    float sA = (s4A[0] + s4A[1]) + (s4A[2] + s4A[3]);
    float sB = (s4B[0] + s4B[1]) + (s4B[2] + s4B[3]);
    sA += __shfl_xor(sA, 16, 64);
    sA += __shfl_xor(sA, 32, 64);
    sB += __shfl_xor(sB, 16, 64);
    sB += __shfl_xor(sB, 32, 64);
    liA += sA; liB += sB;

    // O += P V via 16x16x16: each vf read feeds 2 MFMAs
    __builtin_amdgcn_s_setprio(1);
#pragma unroll
    for (int ks = 0; ks < 8; ++ks)
#pragma unroll
      for (int ft = 0; ft < 4; ++ft) {
        const s16x4 vf = *(const s16x4*)&Vs[(ft * 16 + l16) * 136 + ks * 16 + quad * 4];
        oA[ft] = __builtin_amdgcn_mfma_f32_16x16x16bf16_1k(pA[ks], vf, oA[ft], 0, 0, 0);
        oB[ft] = __builtin_amdgcn_mfma_f32_16x16x16bf16_1k(pB[ks], vf, oB[ft], 0, 0, 0);
      }
    __builtin_amdgcn_s_setprio(0);
  }

  // epilogue: normalize rows (li for qrow=quad*4+r lives at lane quad*4+r)
#pragma unroll
  for (int r = 0; r < 4; ++r) {
    const float invA = 1.0f / __shfl(liA, quad * 4 + r, 64);
    const float invB = 1.0f / __shfl(liB, quad * 4 + r, 64);
    const int rowA = b * T_ + q0 + wid * 32 + quad * 4 + r;
    const int rowB = rowA + 16;
#pragma unroll
    for (int ft = 0; ft < 4; ++ft) {
      out[(size_t)rowA * (3 * D_) + h * DK_ + ft * 16 + l16] = (bf16)(oA[ft][r] * invA);
      out[(size_t)rowB * (3 * D_) + h * DK_ + ft * 16 + l16] = (bf16)(oB[ft][r] * invB);
    }
  }
}

// ---------------- layernorm: one wave per row, in-place, no LDS/barrier ----------------
__global__ __launch_bounds__(256) void ln_out(float* __restrict__ res,
                                              const float* __restrict__ gamma,
                                              const float* __restrict__ beta) {
  const int row = blockIdx.x * 4 + (threadIdx.x >> 6);
  const int lane = threadIdx.x & 63;
  float4 v[4];
  float s = 0.f, q = 0.f;
#pragma unroll
  for (int p = 0; p < 4; ++p) {
    v[p] = *(const float4*)(res + (size_t)row * D_ + p * 256 + lane * 4);
    s += v[p].x + v[p].y + v[p].z + v[p].w;
    q += v[p].x * v[p].x + v[p].y * v[p].y + v[p].z * v[p].z + v[p].w * v[p].w;
  }
#pragma unroll
  for (int m = 1; m < 64; m <<= 1) { s += __shfl_xor(s, m, 64); q += __shfl_xor(q, m, 64); }
  const float mu = s * (1.0f / D_);
  const float var = q * (1.0f / D_) - mu * mu;
  const float rstd = rsqrtf(var + 1e-5f);
#pragma unroll
  for (int p = 0; p < 4; ++p) {
    const int c = p * 256 + lane * 4;
    const float4 g = *(const float4*)(gamma + c);
    const float4 be = *(const float4*)(beta + c);
    float4 ov;
    ov.x = (v[p].x - mu) * rstd * g.x + be.x;
    ov.y = (v[p].y - mu) * rstd * g.y + be.y;
    ov.z = (v[p].z - mu) * rstd * g.z + be.z;
    ov.w = (v[p].w - mu) * rstd * g.w + be.w;
    *(float4*)(res + (size_t)row * D_ + c) = ov;
  }
}

extern "C" void kernel_launch(void* const* d_in, const int* in_sizes, int n_in,
                              void* d_out, int out_size, void* d_ws, size_t ws_size,
                              hipStream_t stream) {
  const float* x     = (const float*)d_in[0];
  const float* Wqkv  = (const float*)d_in[1];
  const float* bqkv  = (const float*)d_in[2];
  const float* Wout  = (const float*)d_in[3];
  const float* bout  = (const float*)d_in[4];
  const float* gamma = (const float*)d_in[5];
  const float* beta  = (const float*)d_in[6];
  float* out = (float*)d_out;  // fp32 residual buffer too (LN in-place)

  // workspace layout (75.5 MB, proven footprint):
  char* ws = (char*)d_ws;
  bf16* WqkvT = (bf16*)ws; ws += (size_t)3 * D_ * D_ * 2;        // [3072][1024]
  bf16* WoutT = (bf16*)ws; ws += (size_t)D_ * D_ * 2;            // [1024][1024]
  bf16* qkv   = (bf16*)ws; ws += (size_t)M_ * 3 * D_ * 2;        // [8192][3072]
  bf16* Vt    = (bf16*)ws;                                       // [4][16][64][2048]
  bf16* attn  = qkv + 2 * D_;  // attn output overwrites qkv's V columns (dead after transpose_v)
  bf16* xb    = Vt;            // x in bf16 aliases Vt (dead before transpose_v runs)

  transpose_wf<<<dim3(D_ / 64, 3 * D_ / 64), 256, 0, stream>>>(Wqkv, WqkvT, D_, 3 * D_);
  transpose_wf<<<dim3(D_ / 64, D_ / 64), 256, 0, stream>>>(Wout, WoutT, D_, D_);
  cast_bf16<<<M_ * D_ / (256 * 8), 256, 0, stream>>>(x, xb);
  gemm128<1, false><<<dim3(M_ / 128, 3 * D_ / 128), 256, 0, stream>>>(
      xb, WqkvT, bqkv, qkv, nullptr, nullptr, 3 * D_, D_, D_, 3 * D_);
  transpose_v<<<B_ * H_ * (T_ / 64), 256, 0, stream>>>(qkv, Vt);
  attn256<<<B_ * H_ * (T_ / 256), 512, 0, stream>>>(qkv, Vt, attn);
  gemm128<1, true><<<dim3(M_ / 128, D_ / 128), 256, 0, stream>>>(
      attn, WoutT, bout, nullptr, out, x, D_, D_, 3 * D_, D_);
  ln_out<<<M_ / 4, 256, 0, stream>>>(out, gamma, beta);
}

// Round 4
// 330.530 us; speedup vs baseline: 1.1162x; 1.0080x over previous
//
#include <hip/hip_runtime.h>

#define B_ 4
#define T_ 2048
#define D_ 1024
#define H_ 16
#define DK_ 64
#define M_ (B_*T_)   // 8192 rows

typedef __bf16 bf16;
typedef __bf16 bf16x8 __attribute__((ext_vector_type(8)));
typedef __bf16 bf16x4 __attribute__((ext_vector_type(4)));
typedef short s16x4 __attribute__((ext_vector_type(4)));
typedef float f32x4 __attribute__((ext_vector_type(4)));

__device__ __forceinline__ f32x4 zero4() { f32x4 v = {0.f, 0.f, 0.f, 0.f}; return v; }

// bare-instruction exp2: exactly 1 VALU issue (s_nop covers the trans-op wait state on SALU)
__device__ __forceinline__ float fexp2(float x) {
  float r;
  asm("v_exp_f32 %0, %1\n\ts_nop 0" : "=v"(r) : "v"(x));
  return r;
}

// 3-input max, 1 VALU issue
__device__ __forceinline__ float max3f(float a, float b, float c) {
  float r;
  asm("v_max3_f32 %0, %1, %2, %3" : "=v"(r) : "v"(a), "v"(b), "v"(c));
  return r;
}

// async global->LDS, 16B per lane; LDS base wave-uniform, HW adds lane*16
__device__ __forceinline__ void g2l16(const void* g, void* l) {
  __builtin_amdgcn_global_load_lds(
      (const __attribute__((address_space(1))) void*)g,
      (__attribute__((address_space(3))) void*)l, 16, 0, 0);
}

// ---------------- x cast: fp32 -> bf16, 8 elems/thread ----------------
__global__ __launch_bounds__(256) void cast_bf16(const float* __restrict__ src,
                                                 bf16* __restrict__ dst) {
  const size_t i = ((size_t)blockIdx.x * 256 + threadIdx.x) * 8;
  float4 a = *(const float4*)(src + i);
  float4 b = *(const float4*)(src + i + 4);
  bf16x8 v;
  v[0] = (bf16)a.x; v[1] = (bf16)a.y; v[2] = (bf16)a.z; v[3] = (bf16)a.w;
  v[4] = (bf16)b.x; v[5] = (bf16)b.y; v[6] = (bf16)b.z; v[7] = (bf16)b.w;
  *(bf16x8*)(dst + i) = v;
}

// ---------------- weight transpose + cast: dst[C][R] = (bf16)src[R][C] ----------------
__global__ __launch_bounds__(256) void transpose_wf(const float* __restrict__ src,
                                                    bf16* __restrict__ dst, int R, int C) {
  __shared__ alignas(16) bf16 ts[64 * 65];
  const int tid = threadIdx.x;
  const int r0 = blockIdx.x * 64, c0 = blockIdx.y * 64;
  {
    int rr = tid >> 2, cc = (tid & 3) * 16;
    const float4* p4 = (const float4*)(src + (size_t)(r0 + rr) * C + c0 + cc);
    float fv[16];
#pragma unroll
    for (int q = 0; q < 4; ++q) *(float4*)&fv[q * 4] = p4[q];
#pragma unroll
    for (int i = 0; i < 16; ++i) ts[(cc + i) * 65 + rr] = (bf16)fv[i];
  }
  __syncthreads();
  {
    int rr = tid >> 2, cc = (tid & 3) * 16;
    bf16x8 a, b;
#pragma unroll
    for (int i = 0; i < 8; ++i) a[i] = ts[rr * 65 + cc + i];
#pragma unroll
    for (int i = 0; i < 8; ++i) b[i] = ts[rr * 65 + cc + 8 + i];
    bf16* q = dst + (size_t)(c0 + rr) * R + r0 + cc;
    *(bf16x8*)q = a;
    *(bf16x8*)(q + 8) = b;
  }
}

// ---------------- V transpose: Vt[b][h][f][t] = qkv[b*T+t][2D + h*64 + f] ----------------
__global__ __launch_bounds__(256) void transpose_v(const bf16* __restrict__ qkv,
                                                   bf16* __restrict__ Vt) {
  __shared__ alignas(16) bf16 ts[64 * 65];
  int bid = blockIdx.x;
  const int tt = bid & 31; bid >>= 5;
  const int h = bid & 15;  const int b = bid >> 4;
  const int t0 = tt * 64;
  const int tid = threadIdx.x;
  {
    int tok = tid >> 2, fc = (tid & 3) * 16;
    const bf16* p = qkv + (size_t)(b * T_ + t0 + tok) * (3 * D_) + 2 * D_ + h * DK_ + fc;
    bf16x8 a = *(const bf16x8*)p;
    bf16x8 c = *(const bf16x8*)(p + 8);
#pragma unroll
    for (int i = 0; i < 8; ++i) ts[(fc + i) * 65 + tok] = a[i];
#pragma unroll
    for (int i = 0; i < 8; ++i) ts[(fc + 8 + i) * 65 + tok] = c[i];
  }
  __syncthreads();
  {
    int f = tid >> 2, tc = (tid & 3) * 16;
    bf16x8 a, c;
#pragma unroll
    for (int i = 0; i < 8; ++i) a[i] = ts[f * 65 + tc + i];
#pragma unroll
    for (int i = 0; i < 8; ++i) c[i] = ts[f * 65 + tc + 8 + i];
    bf16* q = Vt + ((size_t)(b * H_ + h) * DK_ + f) * T_ + t0 + tc;
    *(bf16x8*)q = a;
    *(bf16x8*)(q + 8) = c;
  }
}

// ---------------- GEMM: C[M][N] = A[M][K] @ Bt[N][K]^T + bias ----------------
template <int ASRC, bool FUSE>
__global__ __launch_bounds__(256) void gemm128(const void* __restrict__ Av,
                                               const bf16* __restrict__ Bt,
                                               const float* __restrict__ bias,
                                               bf16* __restrict__ Cbf,
                                               float* __restrict__ Cf,
                                               const float* __restrict__ resid,
                                               int N, int K, int lda, int ldc) {
  __shared__ alignas(16) bf16 As[128 * 32];
  __shared__ alignas(16) bf16 Bs[128 * 32];
  const int tid = threadIdx.x;
  const int wid = tid >> 6, lane = tid & 63, quad = lane >> 4, l16 = lane & 15;
  const int m0 = blockIdx.x * 128, n0 = blockIdx.y * 128;
  const int wr = (wid >> 1) * 64, wc = (wid & 1) * 64;

  f32x4 acc[4][4];
#pragma unroll
  for (int i = 0; i < 4; ++i)
#pragma unroll
    for (int j = 0; j < 4; ++j) acc[i][j] = zero4();

  for (int k0 = 0; k0 < K; k0 += 32) {
    bf16x8 ar[2];
    if (ASRC == 0) {
#pragma unroll
      for (int p = 0; p < 2; ++p) {
        int t = p * 256 + tid;
        int row = t >> 2, kc = (t & 3) * 8;
        const float* ap = (const float*)Av + (size_t)(m0 + row) * lda + k0 + kc;
        float4 a0 = *(const float4*)ap, a1 = *(const float4*)(ap + 4);
        bf16x8 v;
        v[0] = (bf16)a0.x; v[1] = (bf16)a0.y; v[2] = (bf16)a0.z; v[3] = (bf16)a0.w;
        v[4] = (bf16)a1.x; v[5] = (bf16)a1.y; v[6] = (bf16)a1.z; v[7] = (bf16)a1.w;
        ar[p] = v;
      }
    }
    __syncthreads();  // previous iteration's LDS reads complete
#pragma unroll
    for (int p = 0; p < 2; ++p) {
      int t = p * 256 + tid;
      int row = t >> 2, kc = (t & 3) * 8;
      g2l16(Bt + (size_t)(n0 + row) * K + k0 + kc, (char*)Bs + p * 4096 + wid * 1024);
      if (ASRC == 1)
        g2l16((const bf16*)Av + (size_t)(m0 + row) * lda + k0 + kc,
              (char*)As + p * 4096 + wid * 1024);
      else
        *(bf16x8*)&As[row * 32 + kc] = ar[p];
    }
    __syncthreads();
    bf16x8 af[4], bfr[4];
#pragma unroll
    for (int i = 0; i < 4; ++i)
      af[i] = *(const bf16x8*)&As[(wr + i * 16 + l16) * 32 + quad * 8];
#pragma unroll
    for (int j = 0; j < 4; ++j)
      bfr[j] = *(const bf16x8*)&Bs[(wc + j * 16 + l16) * 32 + quad * 8];
#pragma unroll
    for (int i = 0; i < 4; ++i)
#pragma unroll
      for (int j = 0; j < 4; ++j)
        acc[i][j] = __builtin_amdgcn_mfma_f32_16x16x32_bf16(af[i], bfr[j], acc[i][j], 0, 0, 0);
  }

#pragma unroll
  for (int i = 0; i < 4; ++i) {
#pragma unroll
    for (int j = 0; j < 4; ++j) {
      const int col = n0 + wc + j * 16 + l16;
      const float bv = bias[col];
#pragma unroll
      for (int r = 0; r < 4; ++r) {
        const int row = m0 + wr + i * 16 + quad * 4 + r;
        const float v = acc[i][j][r] + bv;
        if (FUSE) {
          const size_t off = (size_t)row * N + col;
          Cf[off] = v + resid[off];
        } else {
          Cbf[(size_t)row * ldc + col] = (bf16)v;
        }
      }
    }
  }
}

// ---------------- flash attention: block = (b, h, 128 q-rows), 4 waves x 32 rows ----------------
// T3 2-phase dbuf via global_load_lds: KV-tile = 64 keys, linear LDS, XOR-swizzled
// source/read (involution: chunk ^= row&7 on both sides). No ds_writes, no staging
// registers -> ~110 VGPR, 32 KB LDS -> 4 blocks/CU (16 waves, 4 independent barrier
// groups). Wave keeps TWO 16-row q-halves so each LDS fragment feeds 2 MFMAs.
__global__ __launch_bounds__(256, 4) void attn_db(const bf16* __restrict__ qkv,
                                                  const bf16* __restrict__ Vt,
                                                  bf16* __restrict__ out) {
  __shared__ alignas(16) bf16 Ks[2][64 * 64];   // [buf][key][f-chunk swz], row = 128 B
  __shared__ alignas(16) bf16 Vs[2][64 * 64];   // [buf][f][key-chunk swz], row = 128 B
  const int tid = threadIdx.x;
  const int wid = tid >> 6, lane = tid & 63, quad = lane >> 4, l16 = lane & 15;
  const int bid = blockIdx.x;
  const int qb = bid & 15, h = (bid >> 4) & 15, b = bid >> 8;
  const int q0 = qb * 128;

  // staging source addrs: lane covers (row = base + lane>>3, 16B chunk = lane&7),
  // source chunk pre-swizzled by row&7 (= lane>>3) so LDS stays linear.
  const int lrow8 = lane >> 3;
  const int kch = (lane & 7) ^ lrow8;
  const bf16* kg = qkv + (size_t)(b * T_ + wid * 16 + lrow8) * (3 * D_) + D_ + h * DK_ + kch * 8;
  const bf16* vg = Vt + ((size_t)(b * H_ + h) * DK_ + wid * 16 + lrow8) * T_ + kch * 8;

  // Q as MFMA B-operand (k=quad*8+j, n=qrow=l16), pre-scaled by log2e/8
  const float SC = 0.125f * 1.44269504f;
  bf16x8 qA[2], qB[2];
  {
    const bf16* qpA = qkv + (size_t)(b * T_ + q0 + wid * 32 + l16) * (3 * D_) + h * DK_ + quad * 8;
    const bf16* qpB = qpA + (size_t)16 * (3 * D_);
    qA[0] = *(const bf16x8*)qpA;       qA[1] = *(const bf16x8*)(qpA + 32);
    qB[0] = *(const bf16x8*)qpB;       qB[1] = *(const bf16x8*)(qpB + 32);
#pragma unroll
    for (int i = 0; i < 8; ++i) {
      qA[0][i] = (bf16)((float)qA[0][i] * SC); qA[1][i] = (bf16)((float)qA[1][i] * SC);
      qB[0][i] = (bf16)((float)qB[0][i] * SC); qB[1][i] = (bf16)((float)qB[1][i] * SC);
    }
  }

  float miA = -1e30f, liA = 0.f, miB = -1e30f, liB = 0.f;
  f32x4 oA[4], oB[4];
#pragma unroll
  for (int ft = 0; ft < 4; ++ft) { oA[ft] = zero4(); oB[ft] = zero4(); }

  // stage: 2 K-issues + 2 V-issues per thread (wave-issue = 1 KB = 8 rows of 128 B)
  auto stage = [&](int buf, int t0) {
    g2l16(kg + (size_t)(t0 + 0) * (3 * D_), &Ks[buf][(wid * 16 + 0) * 64]);
    g2l16(kg + (size_t)(t0 + 8) * (3 * D_), &Ks[buf][(wid * 16 + 8) * 64]);
    g2l16(vg + (size_t)0 * T_ + t0,         &Vs[buf][(wid * 16 + 0) * 64]);
    g2l16(vg + (size_t)8 * T_ + t0,         &Vs[buf][(wid * 16 + 8) * 64]);
  };

  stage(0, 0);
  __syncthreads();   // drains vmcnt -> tile 0 staged

  for (int kt = 0; kt < T_ / 64; ++kt) {
    const int cur = kt & 1;
    if (kt + 1 < T_ / 64) stage(cur ^ 1, (kt + 1) * 64);   // in flight during compute

    // S^T tiles (log2 domain): sv[nt] reg r = S2[key = nt*16+quad*4+r][qrow = l16]
    f32x4 svA[4], svB[4];
#pragma unroll
    for (int nt = 0; nt < 4; ++nt) { svA[nt] = zero4(); svB[nt] = zero4(); }
    __builtin_amdgcn_s_setprio(1);
#pragma unroll
    for (int nt = 0; nt < 4; ++nt)
#pragma unroll
      for (int ks = 0; ks < 2; ++ks) {
        const bf16x8 kf = *(const bf16x8*)
            &Ks[cur][(nt * 16 + l16) * 64 + (((ks << 2) | quad) ^ (l16 & 7)) * 8];
        svA[nt] = __builtin_amdgcn_mfma_f32_16x16x32_bf16(kf, qA[ks], svA[nt], 0, 0, 0);
        svB[nt] = __builtin_amdgcn_mfma_f32_16x16x32_bf16(kf, qB[ks], svB[nt], 0, 0, 0);
      }
    __builtin_amdgcn_s_setprio(0);

    // tile max via parallel v_max3 chains (16 scores per half)
    float a0 = max3f(svA[0][0], svA[0][1], svA[0][2]);
    float a1 = max3f(svA[0][3], svA[1][0], svA[1][1]);
    a0 = max3f(a0, svA[1][2], svA[1][3]);
    a1 = max3f(a1, svA[2][0], svA[2][1]);
    a0 = max3f(a0, svA[2][2], svA[2][3]);
    a1 = max3f(a1, svA[3][0], svA[3][1]);
    a0 = max3f(a0, svA[3][2], svA[3][3]);
    float b0 = max3f(svB[0][0], svB[0][1], svB[0][2]);
    float b1 = max3f(svB[0][3], svB[1][0], svB[1][1]);
    b0 = max3f(b0, svB[1][2], svB[1][3]);
    b1 = max3f(b1, svB[2][0], svB[2][1]);
    b0 = max3f(b0, svB[2][2], svB[2][3]);
    b1 = max3f(b1, svB[3][0], svB[3][1]);
    b0 = max3f(b0, svB[3][2], svB[3][3]);
    float tA = fmaxf(a0, a1), tB = fmaxf(b0, b1);
    tA = fmaxf(tA, __shfl_xor(tA, 16, 64));
    tA = fmaxf(tA, __shfl_xor(tA, 32, 64));
    tB = fmaxf(tB, __shfl_xor(tB, 16, 64));
    tB = fmaxf(tB, __shfl_xor(tB, 32, 64));

    // defer-max (T13), per half
    if (!__all(tA <= miA + 8.f)) {
      const float nm = fmaxf(miA, tA);
      const float al = fexp2(miA - nm);
      miA = nm; liA *= al;
#pragma unroll
      for (int r = 0; r < 4; ++r) {
        const float ar = __shfl(al, quad * 4 + r, 64);
#pragma unroll
        for (int ft = 0; ft < 4; ++ft) oA[ft][r] *= ar;
      }
    }
    if (!__all(tB <= miB + 8.f)) {
      const float nm = fmaxf(miB, tB);
      const float al = fexp2(miB - nm);
      miB = nm; liB *= al;
#pragma unroll
      for (int r = 0; r < 4; ++r) {
        const float ar = __shfl(al, quad * 4 + r, 64);
#pragma unroll
        for (int ft = 0; ft < 4; ++ft) oB[ft][r] *= ar;
      }
    }

    // P = exp2(S - mi); pack to bf16 immediately
    s16x4 pA[4], pB[4];
    f32x4 s4A = zero4(), s4B = zero4();
#pragma unroll
    for (int nt = 0; nt < 4; ++nt) {
      f32x4 dA = svA[nt] - miA;
      dA[0] = fexp2(dA[0]); dA[1] = fexp2(dA[1]); dA[2] = fexp2(dA[2]); dA[3] = fexp2(dA[3]);
      s4A += dA;
      union { bf16x4 b; s16x4 s; } ua;
#pragma unroll
      for (int j = 0; j < 4; ++j) ua.b[j] = (bf16)dA[j];
      pA[nt] = ua.s;
      f32x4 dB = svB[nt] - miB;
      dB[0] = fexp2(dB[0]); dB[1] = fexp2(dB[1]); dB[2] = fexp2(dB[2]); dB[3] = fexp2(dB[3]);
      s4B += dB;
      union { bf16x4 b; s16x4 s; } ub;
#pragma unroll
      for (int j = 0; j < 4; ++j) ub.b[j] = (bf16)dB[j];
      pB[nt] = ub.s;
    }
    float sA = (s4A[0] + s4A[1]) + (s4A[2] + s4A[3]);
    float sB = (s4B[0] + s4B[1]) + (s4B[2] + s4B[3]);
    sA += __shfl_xor(sA, 16, 64);
    sA += __shfl_xor(sA, 32, 64);
    sB += __shfl_xor(sB, 16, 64);
    sB += __shfl_xor(sB, 32, 64);
    liA += sA; liB += sB;

    // O += P V via 16x16x16: each vf read feeds 2 MFMAs
    __builtin_amdgcn_s_setprio(1);
#pragma unroll
    for (int ks = 0; ks < 4; ++ks)
#pragma unroll
      for (int ft = 0; ft < 4; ++ft) {
        const s16x4 vf = *(const s16x4*)
            &Vs[cur][(ft * 16 + l16) * 64 +
                     ((ks * 2 + (quad >> 1)) ^ (l16 & 7)) * 8 + (quad & 1) * 4];
        oA[ft] = __builtin_amdgcn_mfma_f32_16x16x16bf16_1k(pA[ks], vf, oA[ft], 0, 0, 0);
        oB[ft] = __builtin_amdgcn_mfma_f32_16x16x16bf16_1k(pB[ks], vf, oB[ft], 0, 0, 0);
      }
    __builtin_amdgcn_s_setprio(0);

    __syncthreads();   // drains this tile's prefetch (vmcnt 0) + all waves done reading cur
  }

  // epilogue: normalize rows (li for qrow=quad*4+r lives at lane quad*4+r)
#pragma unroll
  for (int r = 0; r < 4; ++r) {
    const float invA = 1.0f / __shfl(liA, quad * 4 + r, 64);
    const float invB = 1.0f / __shfl(liB, quad * 4 + r, 64);
    const int rowA = b * T_ + q0 + wid * 32 + quad * 4 + r;
    const int rowB = rowA + 16;
#pragma unroll
    for (int ft = 0; ft < 4; ++ft) {
      out[(size_t)rowA * (3 * D_) + h * DK_ + ft * 16 + l16] = (bf16)(oA[ft][r] * invA);
      out[(size_t)rowB * (3 * D_) + h * DK_ + ft * 16 + l16] = (bf16)(oB[ft][r] * invB);
    }
  }
}

// ---------------- layernorm: one wave per row, in-place, no LDS/barrier ----------------
__global__ __launch_bounds__(256) void ln_out(float* __restrict__ res,
                                              const float* __restrict__ gamma,
                                              const float* __restrict__ beta) {
  const int row = blockIdx.x * 4 + (threadIdx.x >> 6);
  const int lane = threadIdx.x & 63;
  float4 v[4];
  float s = 0.f, q = 0.f;
#pragma unroll
  for (int p = 0; p < 4; ++p) {
    v[p] = *(const float4*)(res + (size_t)row * D_ + p * 256 + lane * 4);
    s += v[p].x + v[p].y + v[p].z + v[p].w;
    q += v[p].x * v[p].x + v[p].y * v[p].y + v[p].z * v[p].z + v[p].w * v[p].w;
  }
#pragma unroll
  for (int m = 1; m < 64; m <<= 1) { s += __shfl_xor(s, m, 64); q += __shfl_xor(q, m, 64); }
  const float mu = s * (1.0f / D_);
  const float var = q * (1.0f / D_) - mu * mu;
  const float rstd = rsqrtf(var + 1e-5f);
#pragma unroll
  for (int p = 0; p < 4; ++p) {
    const int c = p * 256 + lane * 4;
    const float4 g = *(const float4*)(gamma + c);
    const float4 be = *(const float4*)(beta + c);
    float4 ov;
    ov.x = (v[p].x - mu) * rstd * g.x + be.x;
    ov.y = (v[p].y - mu) * rstd * g.y + be.y;
    ov.z = (v[p].z - mu) * rstd * g.z + be.z;
    ov.w = (v[p].w - mu) * rstd * g.w + be.w;
    *(float4*)(res + (size_t)row * D_ + c) = ov;
  }
}

extern "C" void kernel_launch(void* const* d_in, const int* in_sizes, int n_in,
                              void* d_out, int out_size, void* d_ws, size_t ws_size,
                              hipStream_t stream) {
  const float* x     = (const float*)d_in[0];
  const float* Wqkv  = (const float*)d_in[1];
  const float* bqkv  = (const float*)d_in[2];
  const float* Wout  = (const float*)d_in[3];
  const float* bout  = (const float*)d_in[4];
  const float* gamma = (const float*)d_in[5];
  const float* beta  = (const float*)d_in[6];
  float* out = (float*)d_out;  // fp32 residual buffer too (LN in-place)

  // workspace layout (75.5 MB, proven footprint):
  char* ws = (char*)d_ws;
  bf16* WqkvT = (bf16*)ws; ws += (size_t)3 * D_ * D_ * 2;        // [3072][1024]
  bf16* WoutT = (bf16*)ws; ws += (size_t)D_ * D_ * 2;            // [1024][1024]
  bf16* qkv   = (bf16*)ws; ws += (size_t)M_ * 3 * D_ * 2;        // [8192][3072]
  bf16* Vt    = (bf16*)ws;                                       // [4][16][64][2048]
  bf16* attn  = qkv + 2 * D_;  // attn output overwrites qkv's V columns (dead after transpose_v)
  bf16* xb    = Vt;            // x in bf16 aliases Vt (dead before transpose_v runs)

  transpose_wf<<<dim3(D_ / 64, 3 * D_ / 64), 256, 0, stream>>>(Wqkv, WqkvT, D_, 3 * D_);
  transpose_wf<<<dim3(D_ / 64, D_ / 64), 256, 0, stream>>>(Wout, WoutT, D_, D_);
  cast_bf16<<<M_ * D_ / (256 * 8), 256, 0, stream>>>(x, xb);
  gemm128<1, false><<<dim3(M_ / 128, 3 * D_ / 128), 256, 0, stream>>>(
      xb, WqkvT, bqkv, qkv, nullptr, nullptr, 3 * D_, D_, D_, 3 * D_);
  transpose_v<<<B_ * H_ * (T_ / 64), 256, 0, stream>>>(qkv, Vt);
  attn_db<<<B_ * H_ * (T_ / 128), 256, 0, stream>>>(qkv, Vt, attn);
  gemm128<1, true><<<dim3(M_ / 128, D_ / 128), 256, 0, stream>>>(
      attn, WoutT, bout, nullptr, out, x, D_, D_, 3 * D_, D_);
  ln_out<<<M_ / 4, 256, 0, stream>>>(out, gamma, beta);
}

// Round 5
// 307.537 us; speedup vs baseline: 1.1996x; 1.0748x over previous
//
#include <hip/hip_runtime.h>

#define B_ 4
#define T_ 2048
#define D_ 1024
#define H_ 16
#define DK_ 64
#define M_ (B_*T_)   // 8192 rows

typedef __bf16 bf16;
typedef __bf16 bf16x8 __attribute__((ext_vector_type(8)));
typedef __bf16 bf16x4 __attribute__((ext_vector_type(4)));
typedef short s16x4 __attribute__((ext_vector_type(4)));
typedef float f32x4 __attribute__((ext_vector_type(4)));

__device__ __forceinline__ f32x4 zero4() { f32x4 v = {0.f, 0.f, 0.f, 0.f}; return v; }

// bare-instruction exp2: exactly 1 VALU issue (s_nop covers the trans-op wait state on SALU)
__device__ __forceinline__ float fexp2(float x) {
  float r;
  asm("v_exp_f32 %0, %1\n\ts_nop 0" : "=v"(r) : "v"(x));
  return r;
}

// 3-input max, 1 VALU issue
__device__ __forceinline__ float max3f(float a, float b, float c) {
  float r;
  asm("v_max3_f32 %0, %1, %2, %3" : "=v"(r) : "v"(a), "v"(b), "v"(c));
  return r;
}

// async global->LDS, 16B per lane; LDS base wave-uniform, HW adds lane*16
__device__ __forceinline__ void g2l16(const void* g, void* l) {
  __builtin_amdgcn_global_load_lds(
      (const __attribute__((address_space(1))) void*)g,
      (__attribute__((address_space(3))) void*)l, 16, 0, 0);
}

// ---------------- x cast: fp32 -> bf16, 8 elems/thread ----------------
__global__ __launch_bounds__(256) void cast_bf16(const float* __restrict__ src,
                                                 bf16* __restrict__ dst) {
  const size_t i = ((size_t)blockIdx.x * 256 + threadIdx.x) * 8;
  float4 a = *(const float4*)(src + i);
  float4 b = *(const float4*)(src + i + 4);
  bf16x8 v;
  v[0] = (bf16)a.x; v[1] = (bf16)a.y; v[2] = (bf16)a.z; v[3] = (bf16)a.w;
  v[4] = (bf16)b.x; v[5] = (bf16)b.y; v[6] = (bf16)b.z; v[7] = (bf16)b.w;
  *(bf16x8*)(dst + i) = v;
}

// ---------------- weight transpose + cast: dst[C][R] = (bf16)src[R][C] ----------------
__global__ __launch_bounds__(256) void transpose_wf(const float* __restrict__ src,
                                                    bf16* __restrict__ dst, int R, int C) {
  __shared__ alignas(16) bf16 ts[64 * 65];
  const int tid = threadIdx.x;
  const int r0 = blockIdx.x * 64, c0 = blockIdx.y * 64;
  {
    int rr = tid >> 2, cc = (tid & 3) * 16;
    const float4* p4 = (const float4*)(src + (size_t)(r0 + rr) * C + c0 + cc);
    float fv[16];
#pragma unroll
    for (int q = 0; q < 4; ++q) *(float4*)&fv[q * 4] = p4[q];
#pragma unroll
    for (int i = 0; i < 16; ++i) ts[(cc + i) * 65 + rr] = (bf16)fv[i];
  }
  __syncthreads();
  {
    int rr = tid >> 2, cc = (tid & 3) * 16;
    bf16x8 a, b;
#pragma unroll
    for (int i = 0; i < 8; ++i) a[i] = ts[rr * 65 + cc + i];
#pragma unroll
    for (int i = 0; i < 8; ++i) b[i] = ts[rr * 65 + cc + 8 + i];
    bf16* q = dst + (size_t)(c0 + rr) * R + r0 + cc;
    *(bf16x8*)q = a;
    *(bf16x8*)(q + 8) = b;
  }
}

// ---------------- V transpose: Vt[b][h][f][t] = qkv[b*T+t][2D + h*64 + f] ----------------
__global__ __launch_bounds__(256) void transpose_v(const bf16* __restrict__ qkv,
                                                   bf16* __restrict__ Vt) {
  __shared__ alignas(16) bf16 ts[64 * 65];
  int bid = blockIdx.x;
  const int tt = bid & 31; bid >>= 5;
  const int h = bid & 15;  const int b = bid >> 4;
  const int t0 = tt * 64;
  const int tid = threadIdx.x;
  {
    int tok = tid >> 2, fc = (tid & 3) * 16;
    const bf16* p = qkv + (size_t)(b * T_ + t0 + tok) * (3 * D_) + 2 * D_ + h * DK_ + fc;
    bf16x8 a = *(const bf16x8*)p;
    bf16x8 c = *(const bf16x8*)(p + 8);
#pragma unroll
    for (int i = 0; i < 8; ++i) ts[(fc + i) * 65 + tok] = a[i];
#pragma unroll
    for (int i = 0; i < 8; ++i) ts[(fc + 8 + i) * 65 + tok] = c[i];
  }
  __syncthreads();
  {
    int f = tid >> 2, tc = (tid & 3) * 16;
    bf16x8 a, c;
#pragma unroll
    for (int i = 0; i < 8; ++i) a[i] = ts[f * 65 + tc + i];
#pragma unroll
    for (int i = 0; i < 8; ++i) c[i] = ts[f * 65 + tc + 8 + i];
    bf16* q = Vt + ((size_t)(b * H_ + h) * DK_ + f) * T_ + t0 + tc;
    *(bf16x8*)q = a;
    *(bf16x8*)(q + 8) = c;
  }
}

// ---------------- GEMM BK=64: C[M][N] = A[M][K] @ Bt[N][K]^T + bias ----------------
// Halved barrier count vs BK=32 (m97's ~20% stall is barrier-drain). Row stride
// 128 B would be a 32-bank alias, so: linear global_load_lds dest + source chunk
// pre-swizzled by row&7 + read chunk ^= l16&7 (rule-21 involution). A is bf16.
template <bool FUSE>
__global__ __launch_bounds__(256) void gemm64(const bf16* __restrict__ A,
                                              const bf16* __restrict__ Bt,
                                              const float* __restrict__ bias,
                                              bf16* __restrict__ Cbf,
                                              float* __restrict__ Cf,
                                              const float* __restrict__ resid,
                                              int N, int K, int lda, int ldc) {
  __shared__ alignas(16) bf16 As[128 * 64];
  __shared__ alignas(16) bf16 Bs[128 * 64];
  const int tid = threadIdx.x;
  const int wid = tid >> 6, lane = tid & 63, quad = lane >> 4, l16 = lane & 15;
  const int m0 = blockIdx.x * 128, n0 = blockIdx.y * 128;
  const int wr = (wid >> 1) * 64, wc = (wid & 1) * 64;
  const int sw = l16 & 7;   // read-side swizzle (row&7 of every fragment row)

  f32x4 acc[4][4];
#pragma unroll
  for (int i = 0; i < 4; ++i)
#pragma unroll
    for (int j = 0; j < 4; ++j) acc[i][j] = zero4();

  for (int k0 = 0; k0 < K; k0 += 64) {
    __syncthreads();  // previous iteration's LDS reads complete
#pragma unroll
    for (int p = 0; p < 4; ++p) {
      const int t = p * 256 + tid;
      const int row = t >> 3;
      const int kcs = ((t & 7) ^ (row & 7)) * 8;   // pre-swizzled source chunk
      g2l16(Bt + (size_t)(n0 + row) * K + k0 + kcs, (char*)Bs + p * 4096 + wid * 1024);
      g2l16(A + (size_t)(m0 + row) * lda + k0 + kcs, (char*)As + p * 4096 + wid * 1024);
    }
    __syncthreads();
#pragma unroll
    for (int kk = 0; kk < 2; ++kk) {
      bf16x8 af[4], bfr[4];
#pragma unroll
      for (int i = 0; i < 4; ++i)
        af[i] = *(const bf16x8*)&As[(wr + i * 16 + l16) * 64 + ((((kk << 2) | quad) ^ sw) * 8)];
#pragma unroll
      for (int j = 0; j < 4; ++j)
        bfr[j] = *(const bf16x8*)&Bs[(wc + j * 16 + l16) * 64 + ((((kk << 2) | quad) ^ sw) * 8)];
#pragma unroll
      for (int i = 0; i < 4; ++i)
#pragma unroll
        for (int j = 0; j < 4; ++j)
          acc[i][j] = __builtin_amdgcn_mfma_f32_16x16x32_bf16(af[i], bfr[j], acc[i][j], 0, 0, 0);
    }
  }

#pragma unroll
  for (int i = 0; i < 4; ++i) {
#pragma unroll
    for (int j = 0; j < 4; ++j) {
      const int col = n0 + wc + j * 16 + l16;
      const float bv = bias[col];
#pragma unroll
      for (int r = 0; r < 4; ++r) {
        const int row = m0 + wr + i * 16 + quad * 4 + r;
        const float v = acc[i][j][r] + bv;
        if (FUSE) {
          const size_t off = (size_t)row * N + col;
          Cf[off] = v + resid[off];
        } else {
          Cbf[(size_t)row * ldc + col] = (bf16)v;
        }
      }
    }
  }
}

// ---------------- flash attention: block = (b, h, 128 q-rows), 4 waves x 32 rows ----------------
// R5 softmax diet: (1) defer-max vote on per-lane LOCAL max (no per-tile cross-lane
// reduce; full row-max only inside the rare rescale branch); (2) li kept as per-lane
// f32x4 partials (all components belong to row l16, so rescale uses lane-local alpha
// directly) -- horizontal + cross-quad fold once in the epilogue.
// Removes 12 ds_bpermute + 12 VALU per tile from the critical path.
__global__ __launch_bounds__(256, 4) void attn_db(const bf16* __restrict__ qkv,
                                                  const bf16* __restrict__ Vt,
                                                  bf16* __restrict__ out) {
  __shared__ alignas(16) bf16 Ks[2][64 * 64];   // [buf][key][f-chunk swz], row = 128 B
  __shared__ alignas(16) bf16 Vs[2][64 * 64];   // [buf][f][key-chunk swz], row = 128 B
  const int tid = threadIdx.x;
  const int wid = tid >> 6, lane = tid & 63, quad = lane >> 4, l16 = lane & 15;
  const int bid = blockIdx.x;
  const int qb = bid & 15, h = (bid >> 4) & 15, b = bid >> 8;
  const int q0 = qb * 128;

  // staging source addrs: lane covers (row = base + lane>>3, 16B chunk = lane&7),
  // source chunk pre-swizzled by row&7 (= lane>>3) so LDS stays linear.
  const int lrow8 = lane >> 3;
  const int kch = (lane & 7) ^ lrow8;
  const bf16* kg = qkv + (size_t)(b * T_ + wid * 16 + lrow8) * (3 * D_) + D_ + h * DK_ + kch * 8;
  const bf16* vg = Vt + ((size_t)(b * H_ + h) * DK_ + wid * 16 + lrow8) * T_ + kch * 8;

  // Q as MFMA B-operand (k=quad*8+j, n=qrow=l16), pre-scaled by log2e/8
  const float SC = 0.125f * 1.44269504f;
  bf16x8 qA[2], qB[2];
  {
    const bf16* qpA = qkv + (size_t)(b * T_ + q0 + wid * 32 + l16) * (3 * D_) + h * DK_ + quad * 8;
    const bf16* qpB = qpA + (size_t)16 * (3 * D_);
    qA[0] = *(const bf16x8*)qpA;       qA[1] = *(const bf16x8*)(qpA + 32);
    qB[0] = *(const bf16x8*)qpB;       qB[1] = *(const bf16x8*)(qpB + 32);
#pragma unroll
    for (int i = 0; i < 8; ++i) {
      qA[0][i] = (bf16)((float)qA[0][i] * SC); qA[1][i] = (bf16)((float)qA[1][i] * SC);
      qB[0][i] = (bf16)((float)qB[0][i] * SC); qB[1][i] = (bf16)((float)qB[1][i] * SC);
    }
  }

  float miA = -1e30f, miB = -1e30f;     // row-uniform (qrow = l16)
  f32x4 liA4 = zero4(), liB4 = zero4(); // per-lane partial sums (row l16)
  f32x4 oA[4], oB[4];                   // o[ft][r] = O[qrow=quad*4+r][f=ft*16+l16]
#pragma unroll
  for (int ft = 0; ft < 4; ++ft) { oA[ft] = zero4(); oB[ft] = zero4(); }

  // stage: 2 K-issues + 2 V-issues per thread (wave-issue = 1 KB = 8 rows of 128 B)
  auto stage = [&](int buf, int t0) {
    g2l16(kg + (size_t)(t0 + 0) * (3 * D_), &Ks[buf][(wid * 16 + 0) * 64]);
    g2l16(kg + (size_t)(t0 + 8) * (3 * D_), &Ks[buf][(wid * 16 + 8) * 64]);
    g2l16(vg + (size_t)0 * T_ + t0,         &Vs[buf][(wid * 16 + 0) * 64]);
    g2l16(vg + (size_t)8 * T_ + t0,         &Vs[buf][(wid * 16 + 8) * 64]);
  };

  stage(0, 0);
  __syncthreads();   // drains vmcnt -> tile 0 staged

  for (int kt = 0; kt < T_ / 64; ++kt) {
    const int cur = kt & 1;
    if (kt + 1 < T_ / 64) stage(cur ^ 1, (kt + 1) * 64);   // in flight during compute

    // S^T tiles (log2 domain): sv[nt] reg r = S2[key = nt*16+quad*4+r][qrow = l16]
    f32x4 svA[4], svB[4];
#pragma unroll
    for (int nt = 0; nt < 4; ++nt) { svA[nt] = zero4(); svB[nt] = zero4(); }
    __builtin_amdgcn_s_setprio(1);
#pragma unroll
    for (int nt = 0; nt < 4; ++nt)
#pragma unroll
      for (int ks = 0; ks < 2; ++ks) {
        const bf16x8 kf = *(const bf16x8*)
            &Ks[cur][(nt * 16 + l16) * 64 + (((ks << 2) | quad) ^ (l16 & 7)) * 8];
        svA[nt] = __builtin_amdgcn_mfma_f32_16x16x32_bf16(kf, qA[ks], svA[nt], 0, 0, 0);
        svB[nt] = __builtin_amdgcn_mfma_f32_16x16x32_bf16(kf, qB[ks], svB[nt], 0, 0, 0);
      }
    __builtin_amdgcn_s_setprio(0);

    // per-lane LOCAL max via max3 chains (16 scores per half) -- no cross-lane reduce
    float a0 = max3f(svA[0][0], svA[0][1], svA[0][2]);
    float a1 = max3f(svA[0][3], svA[1][0], svA[1][1]);
    a0 = max3f(a0, svA[1][2], svA[1][3]);
    a1 = max3f(a1, svA[2][0], svA[2][1]);
    a0 = max3f(a0, svA[2][2], svA[2][3]);
    a1 = max3f(a1, svA[3][0], svA[3][1]);
    a0 = max3f(a0, svA[3][2], svA[3][3]);
    float b0 = max3f(svB[0][0], svB[0][1], svB[0][2]);
    float b1 = max3f(svB[0][3], svB[1][0], svB[1][1]);
    b0 = max3f(b0, svB[1][2], svB[1][3]);
    b1 = max3f(b1, svB[2][0], svB[2][1]);
    b0 = max3f(b0, svB[2][2], svB[2][3]);
    b1 = max3f(b1, svB[3][0], svB[3][1]);
    b0 = max3f(b0, svB[3][2], svB[3][3]);
    const float tAl = fmaxf(a0, a1), tBl = fmaxf(b0, b1);

    // defer-max (T13): vote on local max; full row reduce only when triggered (rare)
    if (!__all(tAl <= miA + 8.f)) {
      float tA = fmaxf(tAl, __shfl_xor(tAl, 16, 64));
      tA = fmaxf(tA, __shfl_xor(tA, 32, 64));
      const float nm = fmaxf(miA, tA);
      const float al = fexp2(miA - nm);   // row-uniform for row l16
      miA = nm; liA4 *= al;
#pragma unroll
      for (int r = 0; r < 4; ++r) {
        const float ar = __shfl(al, quad * 4 + r, 64);
#pragma unroll
        for (int ft = 0; ft < 4; ++ft) oA[ft][r] *= ar;
      }
    }
    if (!__all(tBl <= miB + 8.f)) {
      float tB = fmaxf(tBl, __shfl_xor(tBl, 16, 64));
      tB = fmaxf(tB, __shfl_xor(tB, 32, 64));
      const float nm = fmaxf(miB, tB);
      const float al = fexp2(miB - nm);
      miB = nm; liB4 *= al;
#pragma unroll
      for (int r = 0; r < 4; ++r) {
        const float ar = __shfl(al, quad * 4 + r, 64);
#pragma unroll
        for (int ft = 0; ft < 4; ++ft) oB[ft][r] *= ar;
      }
    }

    // P = exp2(S - mi); accumulate per-lane li partials; pack to bf16 immediately
    s16x4 pA[4], pB[4];
#pragma unroll
    for (int nt = 0; nt < 4; ++nt) {
      f32x4 dA = svA[nt] - miA;
      dA[0] = fexp2(dA[0]); dA[1] = fexp2(dA[1]); dA[2] = fexp2(dA[2]); dA[3] = fexp2(dA[3]);
      liA4 += dA;
      union { bf16x4 b; s16x4 s; } ua;
#pragma unroll
      for (int j = 0; j < 4; ++j) ua.b[j] = (bf16)dA[j];
      pA[nt] = ua.s;
      f32x4 dB = svB[nt] - miB;
      dB[0] = fexp2(dB[0]); dB[1] = fexp2(dB[1]); dB[2] = fexp2(dB[2]); dB[3] = fexp2(dB[3]);
      liB4 += dB;
      union { bf16x4 b; s16x4 s; } ub;
#pragma unroll
      for (int j = 0; j < 4; ++j) ub.b[j] = (bf16)dB[j];
      pB[nt] = ub.s;
    }

    // O += P V via 16x16x16: each vf read feeds 2 MFMAs
    __builtin_amdgcn_s_setprio(1);
#pragma unroll
    for (int ks = 0; ks < 4; ++ks)
#pragma unroll
      for (int ft = 0; ft < 4; ++ft) {
        const s16x4 vf = *(const s16x4*)
            &Vs[cur][(ft * 16 + l16) * 64 +
                     ((ks * 2 + (quad >> 1)) ^ (l16 & 7)) * 8 + (quad & 1) * 4];
        oA[ft] = __builtin_amdgcn_mfma_f32_16x16x16bf16_1k(pA[ks], vf, oA[ft], 0, 0, 0);
        oB[ft] = __builtin_amdgcn_mfma_f32_16x16x16bf16_1k(pB[ks], vf, oB[ft], 0, 0, 0);
      }
    __builtin_amdgcn_s_setprio(0);

    __syncthreads();   // drains this tile's prefetch (vmcnt 0) + all waves done reading cur
  }

  // epilogue: fold li partials (once): horizontal + cross-quad for row l16
  float sA = (liA4[0] + liA4[1]) + (liA4[2] + liA4[3]);
  sA += __shfl_xor(sA, 16, 64);
  sA += __shfl_xor(sA, 32, 64);
  float sB = (liB4[0] + liB4[1]) + (liB4[2] + liB4[3]);
  sB += __shfl_xor(sB, 16, 64);
  sB += __shfl_xor(sB, 32, 64);

  // normalize rows (sum for qrow=quad*4+r lives at lane quad*4+r)
#pragma unroll
  for (int r = 0; r < 4; ++r) {
    const float invA = 1.0f / __shfl(sA, quad * 4 + r, 64);
    const float invB = 1.0f / __shfl(sB, quad * 4 + r, 64);
    const int rowA = b * T_ + q0 + wid * 32 + quad * 4 + r;
    const int rowB = rowA + 16;
#pragma unroll
    for (int ft = 0; ft < 4; ++ft) {
      out[(size_t)rowA * (3 * D_) + h * DK_ + ft * 16 + l16] = (bf16)(oA[ft][r] * invA);
      out[(size_t)rowB * (3 * D_) + h * DK_ + ft * 16 + l16] = (bf16)(oB[ft][r] * invB);
    }
  }
}

// ---------------- layernorm: one wave per row, in-place, no LDS/barrier ----------------
__global__ __launch_bounds__(256) void ln_out(float* __restrict__ res,
                                              const float* __restrict__ gamma,
                                              const float* __restrict__ beta) {
  const int row = blockIdx.x * 4 + (threadIdx.x >> 6);
  const int lane = threadIdx.x & 63;
  float4 v[4];
  float s = 0.f, q = 0.f;
#pragma unroll
  for (int p = 0; p < 4; ++p) {
    v[p] = *(const float4*)(res + (size_t)row * D_ + p * 256 + lane * 4);
    s += v[p].x + v[p].y + v[p].z + v[p].w;
    q += v[p].x * v[p].x + v[p].y * v[p].y + v[p].z * v[p].z + v[p].w * v[p].w;
  }
#pragma unroll
  for (int m = 1; m < 64; m <<= 1) { s += __shfl_xor(s, m, 64); q += __shfl_xor(q, m, 64); }
  const float mu = s * (1.0f / D_);
  const float var = q * (1.0f / D_) - mu * mu;
  const float rstd = rsqrtf(var + 1e-5f);
#pragma unroll
  for (int p = 0; p < 4; ++p) {
    const int c = p * 256 + lane * 4;
    const float4 g = *(const float4*)(gamma + c);
    const float4 be = *(const float4*)(beta + c);
    float4 ov;
    ov.x = (v[p].x - mu) * rstd * g.x + be.x;
    ov.y = (v[p].y - mu) * rstd * g.y + be.y;
    ov.z = (v[p].z - mu) * rstd * g.z + be.z;
    ov.w = (v[p].w - mu) * rstd * g.w + be.w;
    *(float4*)(res + (size_t)row * D_ + c) = ov;
  }
}

extern "C" void kernel_launch(void* const* d_in, const int* in_sizes, int n_in,
                              void* d_out, int out_size, void* d_ws, size_t ws_size,
                              hipStream_t stream) {
  const float* x     = (const float*)d_in[0];
  const float* Wqkv  = (const float*)d_in[1];
  const float* bqkv  = (const float*)d_in[2];
  const float* Wout  = (const float*)d_in[3];
  const float* bout  = (const float*)d_in[4];
  const float* gamma = (const float*)d_in[5];
  const float* beta  = (const float*)d_in[6];
  float* out = (float*)d_out;  // fp32 residual buffer too (LN in-place)

  // workspace layout (75.5 MB, proven footprint):
  char* ws = (char*)d_ws;
  bf16* WqkvT = (bf16*)ws; ws += (size_t)3 * D_ * D_ * 2;        // [3072][1024]
  bf16* WoutT = (bf16*)ws; ws += (size_t)D_ * D_ * 2;            // [1024][1024]
  bf16* qkv   = (bf16*)ws; ws += (size_t)M_ * 3 * D_ * 2;        // [8192][3072]
  bf16* Vt    = (bf16*)ws;                                       // [4][16][64][2048]
  bf16* attn  = qkv + 2 * D_;  // attn output overwrites qkv's V columns (dead after transpose_v)
  bf16* xb    = Vt;            // x in bf16 aliases Vt (dead before transpose_v runs)

  transpose_wf<<<dim3(D_ / 64, 3 * D_ / 64), 256, 0, stream>>>(Wqkv, WqkvT, D_, 3 * D_);
  transpose_wf<<<dim3(D_ / 64, D_ / 64), 256, 0, stream>>>(Wout, WoutT, D_, D_);
  cast_bf16<<<M_ * D_ / (256 * 8), 256, 0, stream>>>(x, xb);
  gemm64<false><<<dim3(M_ / 128, 3 * D_ / 128), 256, 0, stream>>>(
      xb, WqkvT, bqkv, qkv, nullptr, nullptr, 3 * D_, D_, D_, 3 * D_);
  transpose_v<<<B_ * H_ * (T_ / 64), 256, 0, stream>>>(qkv, Vt);
  attn_db<<<B_ * H_ * (T_ / 128), 256, 0, stream>>>(qkv, Vt, attn);
  gemm64<true><<<dim3(M_ / 128, D_ / 128), 256, 0, stream>>>(
      attn, WoutT, bout, nullptr, out, x, D_, D_, 3 * D_, D_);
  ln_out<<<M_ / 4, 256, 0, stream>>>(out, gamma, beta);
}

// Round 6
// 299.877 us; speedup vs baseline: 1.2303x; 1.0255x over previous
//
#include <hip/hip_runtime.h>

#define B_ 4
#define T_ 2048
#define D_ 1024
#define H_ 16
#define DK_ 64
#define M_ (B_*T_)   // 8192 rows

typedef __bf16 bf16;
typedef __bf16 bf16x8 __attribute__((ext_vector_type(8)));
typedef __bf16 bf16x4 __attribute__((ext_vector_type(4)));
typedef short s16x4 __attribute__((ext_vector_type(4)));
typedef float f32x4 __attribute__((ext_vector_type(4)));

__device__ __forceinline__ f32x4 zero4() { f32x4 v = {0.f, 0.f, 0.f, 0.f}; return v; }

// bare-instruction exp2: exactly 1 VALU issue (s_nop covers the trans-op wait state on SALU)
__device__ __forceinline__ float fexp2(float x) {
  float r;
  asm("v_exp_f32 %0, %1\n\ts_nop 0" : "=v"(r) : "v"(x));
  return r;
}

// 3-input max, 1 VALU issue
__device__ __forceinline__ float max3f(float a, float b, float c) {
  float r;
  asm("v_max3_f32 %0, %1, %2, %3" : "=v"(r) : "v"(a), "v"(b), "v"(c));
  return r;
}

// async global->LDS, 16B per lane; LDS base wave-uniform, HW adds lane*16
__device__ __forceinline__ void g2l16(const void* g, void* l) {
  __builtin_amdgcn_global_load_lds(
      (const __attribute__((address_space(1))) void*)g,
      (__attribute__((address_space(3))) void*)l, 16, 0, 0);
}

// ---------------- x cast: fp32 -> bf16, 8 elems/thread ----------------
__global__ __launch_bounds__(256) void cast_bf16(const float* __restrict__ src,
                                                 bf16* __restrict__ dst) {
  const size_t i = ((size_t)blockIdx.x * 256 + threadIdx.x) * 8;
  float4 a = *(const float4*)(src + i);
  float4 b = *(const float4*)(src + i + 4);
  bf16x8 v;
  v[0] = (bf16)a.x; v[1] = (bf16)a.y; v[2] = (bf16)a.z; v[3] = (bf16)a.w;
  v[4] = (bf16)b.x; v[5] = (bf16)b.y; v[6] = (bf16)b.z; v[7] = (bf16)b.w;
  *(bf16x8*)(dst + i) = v;
}

// ---------------- weight transpose + cast: dst[C][R] = (bf16)src[R][C] ----------------
__global__ __launch_bounds__(256) void transpose_wf(const float* __restrict__ src,
                                                    bf16* __restrict__ dst, int R, int C) {
  __shared__ alignas(16) bf16 ts[64 * 65];
  const int tid = threadIdx.x;
  const int r0 = blockIdx.x * 64, c0 = blockIdx.y * 64;
  {
    int rr = tid >> 2, cc = (tid & 3) * 16;
    const float4* p4 = (const float4*)(src + (size_t)(r0 + rr) * C + c0 + cc);
    float fv[16];
#pragma unroll
    for (int q = 0; q < 4; ++q) *(float4*)&fv[q * 4] = p4[q];
#pragma unroll
    for (int i = 0; i < 16; ++i) ts[(cc + i) * 65 + rr] = (bf16)fv[i];
  }
  __syncthreads();
  {
    int rr = tid >> 2, cc = (tid & 3) * 16;
    bf16x8 a, b;
#pragma unroll
    for (int i = 0; i < 8; ++i) a[i] = ts[rr * 65 + cc + i];
#pragma unroll
    for (int i = 0; i < 8; ++i) b[i] = ts[rr * 65 + cc + 8 + i];
    bf16* q = dst + (size_t)(c0 + rr) * R + r0 + cc;
    *(bf16x8*)q = a;
    *(bf16x8*)(q + 8) = b;
  }
}

// ---------------- GEMM BK=64: C[M][N] = A[M][K] @ Bt[N][K]^T + bias ----------------
// Linear global_load_lds dest + source chunk pre-swizzled by row&7 + read chunk
// ^= l16&7 (rule-21 involution). A is bf16.
template <bool FUSE>
__global__ __launch_bounds__(256) void gemm64(const bf16* __restrict__ A,
                                              const bf16* __restrict__ Bt,
                                              const float* __restrict__ bias,
                                              bf16* __restrict__ Cbf,
                                              float* __restrict__ Cf,
                                              const float* __restrict__ resid,
                                              int N, int K, int lda, int ldc) {
  __shared__ alignas(16) bf16 As[128 * 64];
  __shared__ alignas(16) bf16 Bs[128 * 64];
  const int tid = threadIdx.x;
  const int wid = tid >> 6, lane = tid & 63, quad = lane >> 4, l16 = lane & 15;
  const int m0 = blockIdx.x * 128, n0 = blockIdx.y * 128;
  const int wr = (wid >> 1) * 64, wc = (wid & 1) * 64;
  const int sw = l16 & 7;   // read-side swizzle (row&7 of every fragment row)

  f32x4 acc[4][4];
#pragma unroll
  for (int i = 0; i < 4; ++i)
#pragma unroll
    for (int j = 0; j < 4; ++j) acc[i][j] = zero4();

  for (int k0 = 0; k0 < K; k0 += 64) {
    __syncthreads();  // previous iteration's LDS reads complete
#pragma unroll
    for (int p = 0; p < 4; ++p) {
      const int t = p * 256 + tid;
      const int row = t >> 3;
      const int kcs = ((t & 7) ^ (row & 7)) * 8;   // pre-swizzled source chunk
      g2l16(Bt + (size_t)(n0 + row) * K + k0 + kcs, (char*)Bs + p * 4096 + wid * 1024);
      g2l16(A + (size_t)(m0 + row) * lda + k0 + kcs, (char*)As + p * 4096 + wid * 1024);
    }
    __syncthreads();
#pragma unroll
    for (int kk = 0; kk < 2; ++kk) {
      bf16x8 af[4], bfr[4];
#pragma unroll
      for (int i = 0; i < 4; ++i)
        af[i] = *(const bf16x8*)&As[(wr + i * 16 + l16) * 64 + ((((kk << 2) | quad) ^ sw) * 8)];
#pragma unroll
      for (int j = 0; j < 4; ++j)
        bfr[j] = *(const bf16x8*)&Bs[(wc + j * 16 + l16) * 64 + ((((kk << 2) | quad) ^ sw) * 8)];
#pragma unroll
      for (int i = 0; i < 4; ++i)
#pragma unroll
        for (int j = 0; j < 4; ++j)
          acc[i][j] = __builtin_amdgcn_mfma_f32_16x16x32_bf16(af[i], bfr[j], acc[i][j], 0, 0, 0);
    }
  }

#pragma unroll
  for (int i = 0; i < 4; ++i) {
#pragma unroll
    for (int j = 0; j < 4; ++j) {
      const int col = n0 + wc + j * 16 + l16;
      const float bv = bias[col];
#pragma unroll
      for (int r = 0; r < 4; ++r) {
        const int row = m0 + wr + i * 16 + quad * 4 + r;
        const float v = acc[i][j][r] + bv;
        if (FUSE) {
          const size_t off = (size_t)row * N + col;
          Cf[off] = v + resid[off];
        } else {
          Cbf[(size_t)row * ldc + col] = (bf16)v;
        }
      }
    }
  }
}

// ---------------- flash attention: block = (b, h, 128 q-rows), 4 waves x 32 rows ----------------
// R6: (1) V staged DIRECTLY from qkv into [key4][fg][4][16] subtiled LDS; PV B-operand
// read via ds_read_b64_tr_b16 (T10) -- transpose_v kernel eliminated. (2) XCD-aware
// bid swizzle (T1): 16 q-blocks sharing one (b,h) K/V panel land on the same XCD L2.
// (3) attn output -> dedicated dense [M][D] buffer (qkv V columns stay live).
__global__ __launch_bounds__(256, 4) void attn_db(const bf16* __restrict__ qkv,
                                                  bf16* __restrict__ ao) {
  __shared__ alignas(16) bf16 Ks[2][4096];   // [buf][key][f-chunk swz], row = 128 B
  __shared__ alignas(16) bf16 Vs2[2][4096];  // [buf][key4][fg][4][16] subtiled for tr_read
  const int tid = threadIdx.x;
  const int wid = tid >> 6, lane = tid & 63, quad = lane >> 4, l16 = lane & 15;
  // XCD swizzle: hw%8 = XCD; give each XCD a contiguous 128-block chunk (8 h-groups)
  const int bid0 = blockIdx.x;
  const int bid = ((bid0 & 7) << 7) | (bid0 >> 3);
  const int qb = bid & 15, h = (bid >> 4) & 15, b = bid >> 8;
  const int q0 = qb * 128;

  // K staging: lane covers (row = lane>>3, 16B chunk = lane&7), source chunk
  // pre-swizzled by row&7 so LDS stays linear (rule-21 involution).
  const int lrow8 = lane >> 3;
  const int kch = (lane & 7) ^ lrow8;
  const bf16* kg = qkv + (size_t)(b * T_ + wid * 16 + lrow8) * (3 * D_) + D_ + h * DK_ + kch * 8;
  // V staging: lane covers token (lane>>5)*4 + ((lane>>1)&3), f chunk
  // ((lane>>3)&3)*16 + (lane&1)*8 -> linear LDS = [key4][fg][r][c] subtiles.
  const int vtok = (lane >> 5) * 4 + ((lane >> 1) & 3);
  const int vfof = ((lane >> 3) & 3) * 16 + (lane & 1) * 8;
  const bf16* vg = qkv + (size_t)(b * T_ + vtok) * (3 * D_) + 2 * D_ + h * DK_ + vfof;
  const unsigned vbase = (unsigned)(uintptr_t)&Vs2[0][0];

  // Q as MFMA B-operand (k=quad*8+j, n=qrow=l16), pre-scaled by log2e/8
  const float SC = 0.125f * 1.44269504f;
  bf16x8 qA[2], qB[2];
  {
    const bf16* qpA = qkv + (size_t)(b * T_ + q0 + wid * 32 + l16) * (3 * D_) + h * DK_ + quad * 8;
    const bf16* qpB = qpA + (size_t)16 * (3 * D_);
    qA[0] = *(const bf16x8*)qpA;       qA[1] = *(const bf16x8*)(qpA + 32);
    qB[0] = *(const bf16x8*)qpB;       qB[1] = *(const bf16x8*)(qpB + 32);
#pragma unroll
    for (int i = 0; i < 8; ++i) {
      qA[0][i] = (bf16)((float)qA[0][i] * SC); qA[1][i] = (bf16)((float)qA[1][i] * SC);
      qB[0][i] = (bf16)((float)qB[0][i] * SC); qB[1][i] = (bf16)((float)qB[1][i] * SC);
    }
  }

  float miA = -1e30f, miB = -1e30f;     // row-uniform (qrow = l16)
  f32x4 liA4 = zero4(), liB4 = zero4(); // per-lane partial sums (row l16)
  f32x4 oA[4], oB[4];                   // o[ft][r] = O[qrow=quad*4+r][f=ft*16+l16]
#pragma unroll
  for (int ft = 0; ft < 4; ++ft) { oA[ft] = zero4(); oB[ft] = zero4(); }

  // stage: 2 K-issues + 2 V-issues per thread (wave-issue = 1 KB linear LDS)
  auto stage = [&](int buf, int t0) {
    g2l16(kg + (size_t)(t0 + 0) * (3 * D_), &Ks[buf][(wid * 16 + 0) * 64]);
    g2l16(kg + (size_t)(t0 + 8) * (3 * D_), &Ks[buf][(wid * 16 + 8) * 64]);
    g2l16(vg + (size_t)(t0 + 0) * (3 * D_),  (char*)&Vs2[buf][0] + (0 + wid * 2) * 512);
    g2l16(vg + (size_t)(t0 + 32) * (3 * D_), (char*)&Vs2[buf][0] + (8 + wid * 2) * 512);
  };

  stage(0, 0);
  __syncthreads();   // drains vmcnt -> tile 0 staged

  for (int kt = 0; kt < T_ / 64; ++kt) {
    const int cur = kt & 1;
    if (kt + 1 < T_ / 64) stage(cur ^ 1, (kt + 1) * 64);   // in flight during compute

    // S^T tiles (log2 domain): sv[nt] reg r = S2[key = nt*16+quad*4+r][qrow = l16]
    f32x4 svA[4], svB[4];
#pragma unroll
    for (int nt = 0; nt < 4; ++nt) { svA[nt] = zero4(); svB[nt] = zero4(); }
    __builtin_amdgcn_s_setprio(1);
#pragma unroll
    for (int nt = 0; nt < 4; ++nt)
#pragma unroll
      for (int ks = 0; ks < 2; ++ks) {
        const bf16x8 kf = *(const bf16x8*)
            &Ks[cur][(nt * 16 + l16) * 64 + (((ks << 2) | quad) ^ (l16 & 7)) * 8];
        svA[nt] = __builtin_amdgcn_mfma_f32_16x16x32_bf16(kf, qA[ks], svA[nt], 0, 0, 0);
        svB[nt] = __builtin_amdgcn_mfma_f32_16x16x32_bf16(kf, qB[ks], svB[nt], 0, 0, 0);
      }
    __builtin_amdgcn_s_setprio(0);

    // per-lane LOCAL max via max3 chains (16 scores per half) -- no cross-lane reduce
    float a0 = max3f(svA[0][0], svA[0][1], svA[0][2]);
    float a1 = max3f(svA[0][3], svA[1][0], svA[1][1]);
    a0 = max3f(a0, svA[1][2], svA[1][3]);
    a1 = max3f(a1, svA[2][0], svA[2][1]);
    a0 = max3f(a0, svA[2][2], svA[2][3]);
    a1 = max3f(a1, svA[3][0], svA[3][1]);
    a0 = max3f(a0, svA[3][2], svA[3][3]);
    float b0 = max3f(svB[0][0], svB[0][1], svB[0][2]);
    float b1 = max3f(svB[0][3], svB[1][0], svB[1][1]);
    b0 = max3f(b0, svB[1][2], svB[1][3]);
    b1 = max3f(b1, svB[2][0], svB[2][1]);
    b0 = max3f(b0, svB[2][2], svB[2][3]);
    b1 = max3f(b1, svB[3][0], svB[3][1]);
    b0 = max3f(b0, svB[3][2], svB[3][3]);
    const float tAl = fmaxf(a0, a1), tBl = fmaxf(b0, b1);

    // defer-max (T13): vote on local max; full row reduce only when triggered (rare)
    if (!__all(tAl <= miA + 8.f)) {
      float tA = fmaxf(tAl, __shfl_xor(tAl, 16, 64));
      tA = fmaxf(tA, __shfl_xor(tA, 32, 64));
      const float nm = fmaxf(miA, tA);
      const float al = fexp2(miA - nm);   // row-uniform for row l16
      miA = nm; liA4 *= al;
#pragma unroll
      for (int r = 0; r < 4; ++r) {
        const float ar = __shfl(al, quad * 4 + r, 64);
#pragma unroll
        for (int ft = 0; ft < 4; ++ft) oA[ft][r] *= ar;
      }
    }
    if (!__all(tBl <= miB + 8.f)) {
      float tB = fmaxf(tBl, __shfl_xor(tBl, 16, 64));
      tB = fmaxf(tB, __shfl_xor(tB, 32, 64));
      const float nm = fmaxf(miB, tB);
      const float al = fexp2(miB - nm);
      miB = nm; liB4 *= al;
#pragma unroll
      for (int r = 0; r < 4; ++r) {
        const float ar = __shfl(al, quad * 4 + r, 64);
#pragma unroll
        for (int ft = 0; ft < 4; ++ft) oB[ft][r] *= ar;
      }
    }

    // P = exp2(S - mi); accumulate per-lane li partials; pack to bf16 immediately
    s16x4 pA[4], pB[4];
#pragma unroll
    for (int nt = 0; nt < 4; ++nt) {
      f32x4 dA = svA[nt] - miA;
      dA[0] = fexp2(dA[0]); dA[1] = fexp2(dA[1]); dA[2] = fexp2(dA[2]); dA[3] = fexp2(dA[3]);
      liA4 += dA;
      union { bf16x4 b; s16x4 s; } ua;
#pragma unroll
      for (int j = 0; j < 4; ++j) ua.b[j] = (bf16)dA[j];
      pA[nt] = ua.s;
      f32x4 dB = svB[nt] - miB;
      dB[0] = fexp2(dB[0]); dB[1] = fexp2(dB[1]); dB[2] = fexp2(dB[2]); dB[3] = fexp2(dB[3]);
      liB4 += dB;
      union { bf16x4 b; s16x4 s; } ub;
#pragma unroll
      for (int j = 0; j < 4; ++j) ub.b[j] = (bf16)dB[j];
      pB[nt] = ub.s;
    }

    // O += P V via 16x16x16; vf via HW transpose read (T10) from subtiled Vs2.
    // Group quad reads block (key4=ks*4+quad, fg=ft): delivered elem j =
    // V[ks*16+quad*4+j][ft*16+l16] == old vf exactly.
    __builtin_amdgcn_s_setprio(1);
    {
      const unsigned va = vbase + (unsigned)cur * 8192u + (unsigned)(quad * 512 + l16 * 8);
#pragma unroll
      for (int ks = 0; ks < 4; ++ks) {
        s16x4 vf[4];
#pragma unroll
        for (int ft = 0; ft < 4; ++ft)
          asm volatile("ds_read_b64_tr_b16 %0, %1 offset:%2"
                       : "=v"(vf[ft]) : "v"(va), "i"(ks * 2048 + ft * 128));
        asm volatile("s_waitcnt lgkmcnt(0)" ::: "memory");
        __builtin_amdgcn_sched_barrier(0);   // rule 18: keep MFMAs after the wait
#pragma unroll
        for (int ft = 0; ft < 4; ++ft) {
          oA[ft] = __builtin_amdgcn_mfma_f32_16x16x16bf16_1k(pA[ks], vf[ft], oA[ft], 0, 0, 0);
          oB[ft] = __builtin_amdgcn_mfma_f32_16x16x16bf16_1k(pB[ks], vf[ft], oB[ft], 0, 0, 0);
        }
      }
    }
    __builtin_amdgcn_s_setprio(0);

    __syncthreads();   // drains this tile's prefetch (vmcnt 0) + all waves done reading cur
  }

  // epilogue: fold li partials (once): horizontal + cross-quad for row l16
  float sA = (liA4[0] + liA4[1]) + (liA4[2] + liA4[3]);
  sA += __shfl_xor(sA, 16, 64);
  sA += __shfl_xor(sA, 32, 64);
  float sB = (liB4[0] + liB4[1]) + (liB4[2] + liB4[3]);
  sB += __shfl_xor(sB, 16, 64);
  sB += __shfl_xor(sB, 32, 64);

  // normalize rows (sum for qrow=quad*4+r lives at lane quad*4+r); dense [M][D] out
#pragma unroll
  for (int r = 0; r < 4; ++r) {
    const float invA = 1.0f / __shfl(sA, quad * 4 + r, 64);
    const float invB = 1.0f / __shfl(sB, quad * 4 + r, 64);
    const int rowA = b * T_ + q0 + wid * 32 + quad * 4 + r;
    const int rowB = rowA + 16;
#pragma unroll
    for (int ft = 0; ft < 4; ++ft) {
      ao[(size_t)rowA * D_ + h * DK_ + ft * 16 + l16] = (bf16)(oA[ft][r] * invA);
      ao[(size_t)rowB * D_ + h * DK_ + ft * 16 + l16] = (bf16)(oB[ft][r] * invB);
    }
  }
}

// ---------------- layernorm: one wave per row, in-place, no LDS/barrier ----------------
__global__ __launch_bounds__(256) void ln_out(float* __restrict__ res,
                                              const float* __restrict__ gamma,
                                              const float* __restrict__ beta) {
  const int row = blockIdx.x * 4 + (threadIdx.x >> 6);
  const int lane = threadIdx.x & 63;
  float4 v[4];
  float s = 0.f, q = 0.f;
#pragma unroll
  for (int p = 0; p < 4; ++p) {
    v[p] = *(const float4*)(res + (size_t)row * D_ + p * 256 + lane * 4);
    s += v[p].x + v[p].y + v[p].z + v[p].w;
    q += v[p].x * v[p].x + v[p].y * v[p].y + v[p].z * v[p].z + v[p].w * v[p].w;
  }
#pragma unroll
  for (int m = 1; m < 64; m <<= 1) { s += __shfl_xor(s, m, 64); q += __shfl_xor(q, m, 64); }
  const float mu = s * (1.0f / D_);
  const float var = q * (1.0f / D_) - mu * mu;
  const float rstd = rsqrtf(var + 1e-5f);
#pragma unroll
  for (int p = 0; p < 4; ++p) {
    const int c = p * 256 + lane * 4;
    const float4 g = *(const float4*)(gamma + c);
    const float4 be = *(const float4*)(beta + c);
    float4 ov;
    ov.x = (v[p].x - mu) * rstd * g.x + be.x;
    ov.y = (v[p].y - mu) * rstd * g.y + be.y;
    ov.z = (v[p].z - mu) * rstd * g.z + be.z;
    ov.w = (v[p].w - mu) * rstd * g.w + be.w;
    *(float4*)(res + (size_t)row * D_ + c) = ov;
  }
}

extern "C" void kernel_launch(void* const* d_in, const int* in_sizes, int n_in,
                              void* d_out, int out_size, void* d_ws, size_t ws_size,
                              hipStream_t stream) {
  const float* x     = (const float*)d_in[0];
  const float* Wqkv  = (const float*)d_in[1];
  const float* bqkv  = (const float*)d_in[2];
  const float* Wout  = (const float*)d_in[3];
  const float* bout  = (const float*)d_in[4];
  const float* gamma = (const float*)d_in[5];
  const float* beta  = (const float*)d_in[6];
  float* out = (float*)d_out;  // fp32 residual buffer too (LN in-place)

  // workspace layout (75.5 MB footprint unchanged):
  char* ws = (char*)d_ws;
  bf16* WqkvT = (bf16*)ws; ws += (size_t)3 * D_ * D_ * 2;        // [3072][1024]
  bf16* WoutT = (bf16*)ws; ws += (size_t)D_ * D_ * 2;            // [1024][1024]
  bf16* qkv   = (bf16*)ws; ws += (size_t)M_ * 3 * D_ * 2;        // [8192][3072]
  bf16* ao    = (bf16*)ws;                                       // [8192][1024] attn out
  bf16* xb    = ao;            // x in bf16 time-shares the slot (dead after QKV gemm)

  transpose_wf<<<dim3(D_ / 64, 3 * D_ / 64), 256, 0, stream>>>(Wqkv, WqkvT, D_, 3 * D_);
  transpose_wf<<<dim3(D_ / 64, D_ / 64), 256, 0, stream>>>(Wout, WoutT, D_, D_);
  cast_bf16<<<M_ * D_ / (256 * 8), 256, 0, stream>>>(x, xb);
  gemm64<false><<<dim3(M_ / 128, 3 * D_ / 128), 256, 0, stream>>>(
      xb, WqkvT, bqkv, qkv, nullptr, nullptr, 3 * D_, D_, D_, 3 * D_);
  attn_db<<<B_ * H_ * (T_ / 128), 256, 0, stream>>>(qkv, ao);
  gemm64<true><<<dim3(M_ / 128, D_ / 128), 256, 0, stream>>>(
      ao, WoutT, bout, nullptr, out, x, D_, D_, D_, D_);
  ln_out<<<M_ / 4, 256, 0, stream>>>(out, gamma, beta);
}

// Round 7
// 298.139 us; speedup vs baseline: 1.2374x; 1.0058x over previous
//
#include <hip/hip_runtime.h>

#define B_ 4
#define T_ 2048
#define D_ 1024
#define H_ 16
#define DK_ 64
#define M_ (B_*T_)   // 8192 rows

typedef __bf16 bf16;
typedef __bf16 bf16x8 __attribute__((ext_vector_type(8)));
typedef __bf16 bf16x4 __attribute__((ext_vector_type(4)));
typedef short s16x4 __attribute__((ext_vector_type(4)));
typedef float f32x4 __attribute__((ext_vector_type(4)));

__device__ __forceinline__ f32x4 zero4() { f32x4 v = {0.f, 0.f, 0.f, 0.f}; return v; }

// bare-instruction exp2: exactly 1 VALU issue (s_nop covers the trans-op wait state on SALU)
__device__ __forceinline__ float fexp2(float x) {
  float r;
  asm("v_exp_f32 %0, %1\n\ts_nop 0" : "=v"(r) : "v"(x));
  return r;
}

// 3-input max, 1 VALU issue
__device__ __forceinline__ float max3f(float a, float b, float c) {
  float r;
  asm("v_max3_f32 %0, %1, %2, %3" : "=v"(r) : "v"(a), "v"(b), "v"(c));
  return r;
}

// async global->LDS, 16B per lane; LDS base wave-uniform, HW adds lane*16
__device__ __forceinline__ void g2l16(const void* g, void* l) {
  __builtin_amdgcn_global_load_lds(
      (const __attribute__((address_space(1))) void*)g,
      (__attribute__((address_space(3))) void*)l, 16, 0, 0);
}

// ---------------- x cast: fp32 -> bf16, 8 elems/thread ----------------
__global__ __launch_bounds__(256) void cast_bf16(const float* __restrict__ src,
                                                 bf16* __restrict__ dst) {
  const size_t i = ((size_t)blockIdx.x * 256 + threadIdx.x) * 8;
  float4 a = *(const float4*)(src + i);
  float4 b = *(const float4*)(src + i + 4);
  bf16x8 v;
  v[0] = (bf16)a.x; v[1] = (bf16)a.y; v[2] = (bf16)a.z; v[3] = (bf16)a.w;
  v[4] = (bf16)b.x; v[5] = (bf16)b.y; v[6] = (bf16)b.z; v[7] = (bf16)b.w;
  *(bf16x8*)(dst + i) = v;
}

// ---------------- weight transpose + cast: dst[C][R] = (bf16)src[R][C] ----------------
__global__ __launch_bounds__(256) void transpose_wf(const float* __restrict__ src,
                                                    bf16* __restrict__ dst, int R, int C) {
  __shared__ alignas(16) bf16 ts[64 * 65];
  const int tid = threadIdx.x;
  const int r0 = blockIdx.x * 64, c0 = blockIdx.y * 64;
  {
    int rr = tid >> 2, cc = (tid & 3) * 16;
    const float4* p4 = (const float4*)(src + (size_t)(r0 + rr) * C + c0 + cc);
    float fv[16];
#pragma unroll
    for (int q = 0; q < 4; ++q) *(float4*)&fv[q * 4] = p4[q];
#pragma unroll
    for (int i = 0; i < 16; ++i) ts[(cc + i) * 65 + rr] = (bf16)fv[i];
  }
  __syncthreads();
  {
    int rr = tid >> 2, cc = (tid & 3) * 16;
    bf16x8 a, b;
#pragma unroll
    for (int i = 0; i < 8; ++i) a[i] = ts[rr * 65 + cc + i];
#pragma unroll
    for (int i = 0; i < 8; ++i) b[i] = ts[rr * 65 + cc + 8 + i];
    bf16* q = dst + (size_t)(c0 + rr) * R + r0 + cc;
    *(bf16x8*)q = a;
    *(bf16x8*)(q + 8) = b;
  }
}

// ---------------- GEMM BK=64: C[M][N] = A[M][K] @ Bt[N][K]^T + bias ----------------
// Linear global_load_lds dest + source chunk pre-swizzled by row&7 + read chunk
// ^= l16&7 (rule-21 involution). A is bf16.
template <bool FUSE>
__global__ __launch_bounds__(256) void gemm64(const bf16* __restrict__ A,
                                              const bf16* __restrict__ Bt,
                                              const float* __restrict__ bias,
                                              bf16* __restrict__ Cbf,
                                              float* __restrict__ Cf,
                                              const float* __restrict__ resid,
                                              int N, int K, int lda, int ldc) {
  __shared__ alignas(16) bf16 As[128 * 64];
  __shared__ alignas(16) bf16 Bs[128 * 64];
  const int tid = threadIdx.x;
  const int wid = tid >> 6, lane = tid & 63, quad = lane >> 4, l16 = lane & 15;
  const int m0 = blockIdx.x * 128, n0 = blockIdx.y * 128;
  const int wr = (wid >> 1) * 64, wc = (wid & 1) * 64;
  const int sw = l16 & 7;   // read-side swizzle (row&7 of every fragment row)

  f32x4 acc[4][4];
#pragma unroll
  for (int i = 0; i < 4; ++i)
#pragma unroll
    for (int j = 0; j < 4; ++j) acc[i][j] = zero4();

  for (int k0 = 0; k0 < K; k0 += 64) {
    __syncthreads();  // previous iteration's LDS reads complete
#pragma unroll
    for (int p = 0; p < 4; ++p) {
      const int t = p * 256 + tid;
      const int row = t >> 3;
      const int kcs = ((t & 7) ^ (row & 7)) * 8;   // pre-swizzled source chunk
      g2l16(Bt + (size_t)(n0 + row) * K + k0 + kcs, (char*)Bs + p * 4096 + wid * 1024);
      g2l16(A + (size_t)(m0 + row) * lda + k0 + kcs, (char*)As + p * 4096 + wid * 1024);
    }
    __syncthreads();
#pragma unroll
    for (int kk = 0; kk < 2; ++kk) {
      bf16x8 af[4], bfr[4];
#pragma unroll
      for (int i = 0; i < 4; ++i)
        af[i] = *(const bf16x8*)&As[(wr + i * 16 + l16) * 64 + ((((kk << 2) | quad) ^ sw) * 8)];
#pragma unroll
      for (int j = 0; j < 4; ++j)
        bfr[j] = *(const bf16x8*)&Bs[(wc + j * 16 + l16) * 64 + ((((kk << 2) | quad) ^ sw) * 8)];
#pragma unroll
      for (int i = 0; i < 4; ++i)
#pragma unroll
        for (int j = 0; j < 4; ++j)
          acc[i][j] = __builtin_amdgcn_mfma_f32_16x16x32_bf16(af[i], bfr[j], acc[i][j], 0, 0, 0);
    }
  }

#pragma unroll
  for (int i = 0; i < 4; ++i) {
#pragma unroll
    for (int j = 0; j < 4; ++j) {
      const int col = n0 + wc + j * 16 + l16;
      const float bv = bias[col];
#pragma unroll
      for (int r = 0; r < 4; ++r) {
        const int row = m0 + wr + i * 16 + quad * 4 + r;
        const float v = acc[i][j][r] + bv;
        if (FUSE) {
          const size_t off = (size_t)row * N + col;
          Cf[off] = v + resid[off];
        } else {
          Cbf[(size_t)row * ldc + col] = (bf16)v;
        }
      }
    }
  }
}

// ---------------- flash attention: block = (b, h, 128 q-rows), 4 waves x 32 rows ----------------
// R7: FIX V-staging wave offset. Each wave's g2l16 dest covers LDS key4 slots
// {wid*2, wid*2+1} (tokens wid*8..wid*8+7), so the global source token must include
// wid*8 -- R6 omitted it, duplicating tokens 0-7/32-39 across all key4 slots
// (absmax 0.0156 -> 0.0625 was the symptom; diffuse softmax masked the rest).
__global__ __launch_bounds__(256, 4) void attn_db(const bf16* __restrict__ qkv,
                                                  bf16* __restrict__ ao) {
  __shared__ alignas(16) bf16 Ks[2][4096];   // [buf][key][f-chunk swz], row = 128 B
  __shared__ alignas(16) bf16 Vs2[2][4096];  // [buf][key4][fg][4][16] subtiled for tr_read
  const int tid = threadIdx.x;
  const int wid = tid >> 6, lane = tid & 63, quad = lane >> 4, l16 = lane & 15;
  // XCD swizzle: hw%8 = XCD; give each XCD a contiguous 128-block chunk (8 h-groups)
  const int bid0 = blockIdx.x;
  const int bid = ((bid0 & 7) << 7) | (bid0 >> 3);
  const int qb = bid & 15, h = (bid >> 4) & 15, b = bid >> 8;
  const int q0 = qb * 128;

  // K staging: lane covers (row = lane>>3, 16B chunk = lane&7), source chunk
  // pre-swizzled by row&7 so LDS stays linear (rule-21 involution).
  const int lrow8 = lane >> 3;
  const int kch = (lane & 7) ^ lrow8;
  const bf16* kg = qkv + (size_t)(b * T_ + wid * 16 + lrow8) * (3 * D_) + D_ + h * DK_ + kch * 8;
  // V staging: wave wid's issue fills key4 slots {wid*2+(lane>>5)} (+8 for issue 2),
  // i.e. tokens wid*8 + (lane>>5)*4 + r with r=(lane>>1)&3; f chunk
  // ((lane>>3)&3)*16 + (lane&1)*8 -> linear LDS = [key4][fg][r][c] subtiles.
  const int vtok = wid * 8 + (lane >> 5) * 4 + ((lane >> 1) & 3);   // R7 fix: + wid*8
  const int vfof = ((lane >> 3) & 3) * 16 + (lane & 1) * 8;
  const bf16* vg = qkv + (size_t)(b * T_ + vtok) * (3 * D_) + 2 * D_ + h * DK_ + vfof;
  const unsigned vbase = (unsigned)(uintptr_t)&Vs2[0][0];

  // Q as MFMA B-operand (k=quad*8+j, n=qrow=l16), pre-scaled by log2e/8
  const float SC = 0.125f * 1.44269504f;
  bf16x8 qA[2], qB[2];
  {
    const bf16* qpA = qkv + (size_t)(b * T_ + q0 + wid * 32 + l16) * (3 * D_) + h * DK_ + quad * 8;
    const bf16* qpB = qpA + (size_t)16 * (3 * D_);
    qA[0] = *(const bf16x8*)qpA;       qA[1] = *(const bf16x8*)(qpA + 32);
    qB[0] = *(const bf16x8*)qpB;       qB[1] = *(const bf16x8*)(qpB + 32);
#pragma unroll
    for (int i = 0; i < 8; ++i) {
      qA[0][i] = (bf16)((float)qA[0][i] * SC); qA[1][i] = (bf16)((float)qA[1][i] * SC);
      qB[0][i] = (bf16)((float)qB[0][i] * SC); qB[1][i] = (bf16)((float)qB[1][i] * SC);
    }
  }

  float miA = -1e30f, miB = -1e30f;     // row-uniform (qrow = l16)
  f32x4 liA4 = zero4(), liB4 = zero4(); // per-lane partial sums (row l16)
  f32x4 oA[4], oB[4];                   // o[ft][r] = O[qrow=quad*4+r][f=ft*16+l16]
#pragma unroll
  for (int ft = 0; ft < 4; ++ft) { oA[ft] = zero4(); oB[ft] = zero4(); }

  // stage: 2 K-issues + 2 V-issues per thread (wave-issue = 1 KB linear LDS)
  auto stage = [&](int buf, int t0) {
    g2l16(kg + (size_t)(t0 + 0) * (3 * D_), &Ks[buf][(wid * 16 + 0) * 64]);
    g2l16(kg + (size_t)(t0 + 8) * (3 * D_), &Ks[buf][(wid * 16 + 8) * 64]);
    g2l16(vg + (size_t)(t0 + 0) * (3 * D_),  (char*)&Vs2[buf][0] + (0 + wid * 2) * 512);
    g2l16(vg + (size_t)(t0 + 32) * (3 * D_), (char*)&Vs2[buf][0] + (8 + wid * 2) * 512);
  };

  stage(0, 0);
  __syncthreads();   // drains vmcnt -> tile 0 staged

  for (int kt = 0; kt < T_ / 64; ++kt) {
    const int cur = kt & 1;
    if (kt + 1 < T_ / 64) stage(cur ^ 1, (kt + 1) * 64);   // in flight during compute

    // S^T tiles (log2 domain): sv[nt] reg r = S2[key = nt*16+quad*4+r][qrow = l16]
    f32x4 svA[4], svB[4];
#pragma unroll
    for (int nt = 0; nt < 4; ++nt) { svA[nt] = zero4(); svB[nt] = zero4(); }
    __builtin_amdgcn_s_setprio(1);
#pragma unroll
    for (int nt = 0; nt < 4; ++nt)
#pragma unroll
      for (int ks = 0; ks < 2; ++ks) {
        const bf16x8 kf = *(const bf16x8*)
            &Ks[cur][(nt * 16 + l16) * 64 + (((ks << 2) | quad) ^ (l16 & 7)) * 8];
        svA[nt] = __builtin_amdgcn_mfma_f32_16x16x32_bf16(kf, qA[ks], svA[nt], 0, 0, 0);
        svB[nt] = __builtin_amdgcn_mfma_f32_16x16x32_bf16(kf, qB[ks], svB[nt], 0, 0, 0);
      }
    __builtin_amdgcn_s_setprio(0);

    // per-lane LOCAL max via max3 chains (16 scores per half) -- no cross-lane reduce
    float a0 = max3f(svA[0][0], svA[0][1], svA[0][2]);
    float a1 = max3f(svA[0][3], svA[1][0], svA[1][1]);
    a0 = max3f(a0, svA[1][2], svA[1][3]);
    a1 = max3f(a1, svA[2][0], svA[2][1]);
    a0 = max3f(a0, svA[2][2], svA[2][3]);
    a1 = max3f(a1, svA[3][0], svA[3][1]);
    a0 = max3f(a0, svA[3][2], svA[3][3]);
    float b0 = max3f(svB[0][0], svB[0][1], svB[0][2]);
    float b1 = max3f(svB[0][3], svB[1][0], svB[1][1]);
    b0 = max3f(b0, svB[1][2], svB[1][3]);
    b1 = max3f(b1, svB[2][0], svB[2][1]);
    b0 = max3f(b0, svB[2][2], svB[2][3]);
    b1 = max3f(b1, svB[3][0], svB[3][1]);
    b0 = max3f(b0, svB[3][2], svB[3][3]);
    const float tAl = fmaxf(a0, a1), tBl = fmaxf(b0, b1);

    // defer-max (T13): vote on local max; full row reduce only when triggered (rare)
    if (!__all(tAl <= miA + 8.f)) {
      float tA = fmaxf(tAl, __shfl_xor(tAl, 16, 64));
      tA = fmaxf(tA, __shfl_xor(tA, 32, 64));
      const float nm = fmaxf(miA, tA);
      const float al = fexp2(miA - nm);   // row-uniform for row l16
      miA = nm; liA4 *= al;
#pragma unroll
      for (int r = 0; r < 4; ++r) {
        const float ar = __shfl(al, quad * 4 + r, 64);
#pragma unroll
        for (int ft = 0; ft < 4; ++ft) oA[ft][r] *= ar;
      }
    }
    if (!__all(tBl <= miB + 8.f)) {
      float tB = fmaxf(tBl, __shfl_xor(tBl, 16, 64));
      tB = fmaxf(tB, __shfl_xor(tB, 32, 64));
      const float nm = fmaxf(miB, tB);
      const float al = fexp2(miB - nm);
      miB = nm; liB4 *= al;
#pragma unroll
      for (int r = 0; r < 4; ++r) {
        const float ar = __shfl(al, quad * 4 + r, 64);
#pragma unroll
        for (int ft = 0; ft < 4; ++ft) oB[ft][r] *= ar;
      }
    }

    // P = exp2(S - mi); accumulate per-lane li partials; pack to bf16 immediately
    s16x4 pA[4], pB[4];
#pragma unroll
    for (int nt = 0; nt < 4; ++nt) {
      f32x4 dA = svA[nt] - miA;
      dA[0] = fexp2(dA[0]); dA[1] = fexp2(dA[1]); dA[2] = fexp2(dA[2]); dA[3] = fexp2(dA[3]);
      liA4 += dA;
      union { bf16x4 b; s16x4 s; } ua;
#pragma unroll
      for (int j = 0; j < 4; ++j) ua.b[j] = (bf16)dA[j];
      pA[nt] = ua.s;
      f32x4 dB = svB[nt] - miB;
      dB[0] = fexp2(dB[0]); dB[1] = fexp2(dB[1]); dB[2] = fexp2(dB[2]); dB[3] = fexp2(dB[3]);
      liB4 += dB;
      union { bf16x4 b; s16x4 s; } ub;
#pragma unroll
      for (int j = 0; j < 4; ++j) ub.b[j] = (bf16)dB[j];
      pB[nt] = ub.s;
    }

    // O += P V via 16x16x16; vf via HW transpose read (T10) from subtiled Vs2.
    // Group quad reads block (key4=ks*4+quad, fg=ft): delivered elem j =
    // V[ks*16+quad*4+j][ft*16+l16] == the PV B-operand exactly.
    __builtin_amdgcn_s_setprio(1);
    {
      const unsigned va = vbase + (unsigned)cur * 8192u + (unsigned)(quad * 512 + l16 * 8);
#pragma unroll
      for (int ks = 0; ks < 4; ++ks) {
        s16x4 vf[4];
#pragma unroll
        for (int ft = 0; ft < 4; ++ft)
          asm volatile("ds_read_b64_tr_b16 %0, %1 offset:%2"
                       : "=v"(vf[ft]) : "v"(va), "i"(ks * 2048 + ft * 128));
        asm volatile("s_waitcnt lgkmcnt(0)" ::: "memory");
        __builtin_amdgcn_sched_barrier(0);   // rule 18: keep MFMAs after the wait
#pragma unroll
        for (int ft = 0; ft < 4; ++ft) {
          oA[ft] = __builtin_amdgcn_mfma_f32_16x16x16bf16_1k(pA[ks], vf[ft], oA[ft], 0, 0, 0);
          oB[ft] = __builtin_amdgcn_mfma_f32_16x16x16bf16_1k(pB[ks], vf[ft], oB[ft], 0, 0, 0);
        }
      }
    }
    __builtin_amdgcn_s_setprio(0);

    __syncthreads();   // drains this tile's prefetch (vmcnt 0) + all waves done reading cur
  }

  // epilogue: fold li partials (once): horizontal + cross-quad for row l16
  float sA = (liA4[0] + liA4[1]) + (liA4[2] + liA4[3]);
  sA += __shfl_xor(sA, 16, 64);
  sA += __shfl_xor(sA, 32, 64);
  float sB = (liB4[0] + liB4[1]) + (liB4[2] + liB4[3]);
  sB += __shfl_xor(sB, 16, 64);
  sB += __shfl_xor(sB, 32, 64);

  // normalize rows (sum for qrow=quad*4+r lives at lane quad*4+r); dense [M][D] out
#pragma unroll
  for (int r = 0; r < 4; ++r) {
    const float invA = 1.0f / __shfl(sA, quad * 4 + r, 64);
    const float invB = 1.0f / __shfl(sB, quad * 4 + r, 64);
    const int rowA = b * T_ + q0 + wid * 32 + quad * 4 + r;
    const int rowB = rowA + 16;
#pragma unroll
    for (int ft = 0; ft < 4; ++ft) {
      ao[(size_t)rowA * D_ + h * DK_ + ft * 16 + l16] = (bf16)(oA[ft][r] * invA);
      ao[(size_t)rowB * D_ + h * DK_ + ft * 16 + l16] = (bf16)(oB[ft][r] * invB);
    }
  }
}

// ---------------- layernorm: one wave per row, in-place, no LDS/barrier ----------------
__global__ __launch_bounds__(256) void ln_out(float* __restrict__ res,
                                              const float* __restrict__ gamma,
                                              const float* __restrict__ beta) {
  const int row = blockIdx.x * 4 + (threadIdx.x >> 6);
  const int lane = threadIdx.x & 63;
  float4 v[4];
  float s = 0.f, q = 0.f;
#pragma unroll
  for (int p = 0; p < 4; ++p) {
    v[p] = *(const float4*)(res + (size_t)row * D_ + p * 256 + lane * 4);
    s += v[p].x + v[p].y + v[p].z + v[p].w;
    q += v[p].x * v[p].x + v[p].y * v[p].y + v[p].z * v[p].z + v[p].w * v[p].w;
  }
#pragma unroll
  for (int m = 1; m < 64; m <<= 1) { s += __shfl_xor(s, m, 64); q += __shfl_xor(q, m, 64); }
  const float mu = s * (1.0f / D_);
  const float var = q * (1.0f / D_) - mu * mu;
  const float rstd = rsqrtf(var + 1e-5f);
#pragma unroll
  for (int p = 0; p < 4; ++p) {
    const int c = p * 256 + lane * 4;
    const float4 g = *(const float4*)(gamma + c);
    const float4 be = *(const float4*)(beta + c);
    float4 ov;
    ov.x = (v[p].x - mu) * rstd * g.x + be.x;
    ov.y = (v[p].y - mu) * rstd * g.y + be.y;
    ov.z = (v[p].z - mu) * rstd * g.z + be.z;
    ov.w = (v[p].w - mu) * rstd * g.w + be.w;
    *(float4*)(res + (size_t)row * D_ + c) = ov;
  }
}

extern "C" void kernel_launch(void* const* d_in, const int* in_sizes, int n_in,
                              void* d_out, int out_size, void* d_ws, size_t ws_size,
                              hipStream_t stream) {
  const float* x     = (const float*)d_in[0];
  const float* Wqkv  = (const float*)d_in[1];
  const float* bqkv  = (const float*)d_in[2];
  const float* Wout  = (const float*)d_in[3];
  const float* bout  = (const float*)d_in[4];
  const float* gamma = (const float*)d_in[5];
  const float* beta  = (const float*)d_in[6];
  float* out = (float*)d_out;  // fp32 residual buffer too (LN in-place)

  // workspace layout (75.5 MB footprint unchanged):
  char* ws = (char*)d_ws;
  bf16* WqkvT = (bf16*)ws; ws += (size_t)3 * D_ * D_ * 2;        // [3072][1024]
  bf16* WoutT = (bf16*)ws; ws += (size_t)D_ * D_ * 2;            // [1024][1024]
  bf16* qkv   = (bf16*)ws; ws += (size_t)M_ * 3 * D_ * 2;        // [8192][3072]
  bf16* ao    = (bf16*)ws;                                       // [8192][1024] attn out
  bf16* xb    = ao;            // x in bf16 time-shares the slot (dead after QKV gemm)

  transpose_wf<<<dim3(D_ / 64, 3 * D_ / 64), 256, 0, stream>>>(Wqkv, WqkvT, D_, 3 * D_);
  transpose_wf<<<dim3(D_ / 64, D_ / 64), 256, 0, stream>>>(Wout, WoutT, D_, D_);
  cast_bf16<<<M_ * D_ / (256 * 8), 256, 0, stream>>>(x, xb);
  gemm64<false><<<dim3(M_ / 128, 3 * D_ / 128), 256, 0, stream>>>(
      xb, WqkvT, bqkv, qkv, nullptr, nullptr, 3 * D_, D_, D_, 3 * D_);
  attn_db<<<B_ * H_ * (T_ / 128), 256, 0, stream>>>(qkv, ao);
  gemm64<true><<<dim3(M_ / 128, D_ / 128), 256, 0, stream>>>(
      ao, WoutT, bout, nullptr, out, x, D_, D_, D_, D_);
  ln_out<<<M_ / 4, 256, 0, stream>>>(out, gamma, beta);
}